// Round 13
// baseline (285.636 us; speedup 1.0000x reference)
//
#include <hip/hip_runtime.h>

#define DIM 128
#define NB 512            // binning grid blocks (pass A/B)

typedef short v8s __attribute__((ext_vector_type(8)));
typedef float v4f __attribute__((ext_vector_type(4)));

__device__ __forceinline__ unsigned short f2bf(float f) {
    unsigned int x = __float_as_uint(f);
    unsigned int r = ((x >> 16) & 1u) + 0x7fffu;
    return (unsigned short)((x + r) >> 16);
}
__device__ __forceinline__ float bf2f(short s) {
    return __uint_as_float(((unsigned)(unsigned short)s) << 16);
}

// ======================= binned CSR build (no global atomics) =======================

__global__ __launch_bounds__(256) void k_binA(const int* __restrict__ rows, const int* __restrict__ cols,
                                              int* __restrict__ Mu, int* __restrict__ Mi,
                                              int nnz, int chunk, int nbu, int nbi, int shu, int shi)
{
    __shared__ int hu[256], hi[256];
    int k = blockIdx.x, t = threadIdx.x;
    for (int j = t; j < nbu; j += 256) hu[j] = 0;
    for (int j = t; j < nbi; j += 256) hi[j] = 0;
    __syncthreads();
    int beg = k * chunk, end = min(beg + chunk, nnz);
    if (beg < end) {
        int beg4 = beg >> 2, end4 = end >> 2;
        for (int e4 = beg4 + t; e4 < end4; e4 += 256) {
            int4 r = reinterpret_cast<const int4*>(rows)[e4];
            int4 c = reinterpret_cast<const int4*>(cols)[e4];
            atomicAdd(&hu[r.x >> shu], 1); atomicAdd(&hu[r.y >> shu], 1);
            atomicAdd(&hu[r.z >> shu], 1); atomicAdd(&hu[r.w >> shu], 1);
            atomicAdd(&hi[c.x >> shi], 1); atomicAdd(&hi[c.y >> shi], 1);
            atomicAdd(&hi[c.z >> shi], 1); atomicAdd(&hi[c.w >> shi], 1);
        }
        for (int e = (end4 << 2) + t; e < end; e += 256) {
            atomicAdd(&hu[rows[e] >> shu], 1);
            atomicAdd(&hi[cols[e] >> shi], 1);
        }
    }
    __syncthreads();
    for (int j = t; j < nbu; j += 256) Mu[k * nbu + j] = hu[j];
    for (int j = t; j < nbi; j += 256) Mi[k * nbi + j] = hi[j];
}

__global__ __launch_bounds__(256) void k_binS1(int* __restrict__ M, int* __restrict__ tot,
                                               int nb, int nblk)
{
    __shared__ int ps[256];
    int j = blockIdx.x, t = threadIdx.x;
    int i0 = 2 * t, i1 = 2 * t + 1;
    int v0 = (i0 < nblk) ? M[i0 * nb + j] : 0;
    int v1 = (i1 < nblk) ? M[i1 * nb + j] : 0;
    ps[t] = v0 + v1;
    __syncthreads();
    for (int off = 1; off < 256; off <<= 1) {
        int x = (t >= off) ? ps[t - off] : 0;
        __syncthreads();
        ps[t] += x;
        __syncthreads();
    }
    int ep = ps[t] - (v0 + v1);
    if (i0 < nblk) M[i0 * nb + j] = ep;
    if (i1 < nblk) M[i1 * nb + j] = ep + v0;
    if (t == 255) tot[j] = ps[255];
}

__global__ __launch_bounds__(256) void k_binS2(const int* __restrict__ tot, int* __restrict__ base, int nb)
{
    __shared__ int s[256];
    int t = threadIdx.x;
    int v = (t < nb) ? tot[t] : 0;
    s[t] = v;
    __syncthreads();
    for (int off = 1; off < 256; off <<= 1) {
        int x = (t >= off) ? s[t - off] : 0;
        __syncthreads();
        s[t] += x;
        __syncthreads();
    }
    if (t < nb) base[t] = s[t] - v;
    if (t == 255) base[nb] = s[255];
}

__global__ __launch_bounds__(256) void k_binB(const int* __restrict__ rows, const int* __restrict__ cols,
                                              const float* __restrict__ vals,
                                              const int* __restrict__ Mu, const int* __restrict__ Mi,
                                              const int* __restrict__ base_u, const int* __restrict__ base_i,
                                              int2* __restrict__ bu, int2* __restrict__ bi,
                                              int nnz, int chunk, int nbu, int nbi, int shu, int shi)
{
    __shared__ int cu[256], ci[256];
    int k = blockIdx.x, t = threadIdx.x;
    for (int j = t; j < nbu; j += 256) cu[j] = Mu[k * nbu + j] + base_u[j];
    for (int j = t; j < nbi; j += 256) ci[j] = Mi[k * nbi + j] + base_i[j];
    __syncthreads();
    int mu = (1 << shu) - 1, mi = (1 << shi) - 1;
    int beg = k * chunk, end = min(beg + chunk, nnz);
    if (beg >= end) return;
    int beg4 = beg >> 2, end4 = end >> 2;
    for (int e4 = beg4 + t; e4 < end4; e4 += 256) {
        int4 r = reinterpret_cast<const int4*>(rows)[e4];
        int4 c = reinterpret_cast<const int4*>(cols)[e4];
        int4 v = reinterpret_cast<const int4*>(vals)[e4];
        int p;
        p = atomicAdd(&cu[r.x >> shu], 1); bu[p] = make_int2((c.x << shu) | (r.x & mu), v.x);
        p = atomicAdd(&ci[c.x >> shi], 1); bi[p] = make_int2((r.x << shi) | (c.x & mi), v.x);
        p = atomicAdd(&cu[r.y >> shu], 1); bu[p] = make_int2((c.y << shu) | (r.y & mu), v.y);
        p = atomicAdd(&ci[c.y >> shi], 1); bi[p] = make_int2((r.y << shi) | (c.y & mi), v.y);
        p = atomicAdd(&cu[r.z >> shu], 1); bu[p] = make_int2((c.z << shu) | (r.z & mu), v.z);
        p = atomicAdd(&ci[c.z >> shi], 1); bi[p] = make_int2((r.z << shi) | (c.z & mi), v.z);
        p = atomicAdd(&cu[r.w >> shu], 1); bu[p] = make_int2((c.w << shu) | (r.w & mu), v.w);
        p = atomicAdd(&ci[c.w >> shi], 1); bi[p] = make_int2((r.w << shi) | (c.w & mi), v.w);
    }
    for (int e = (end4 << 2) + t; e < end; e += 256) {
        int r = rows[e], c = cols[e];
        int v = reinterpret_cast<const int*>(vals)[e];
        int p;
        p = atomicAdd(&cu[r >> shu], 1); bu[p] = make_int2((c << shu) | (r & mu), v);
        p = atomicAdd(&ci[c >> shi], 1); bi[p] = make_int2((r << shi) | (c & mi), v);
    }
}

__global__ __launch_bounds__(256) void k_binC(const int2* __restrict__ binned,
                                              const int* __restrict__ base,
                                              int* __restrict__ ptr, int2* __restrict__ cs,
                                              int nrows, int sh, int total)
{
    __shared__ int hist[512];
    __shared__ int scn[512];
    __shared__ int psum[256];
    int j = blockIdx.x, t = threadIdx.x;
    int BR = 1 << sh;
    int row0 = j << sh;
    int beg = base[j], end = base[j + 1];
    for (int r = t; r < BR; r += 256) hist[r] = 0;
    __syncthreads();
    for (int e = beg + t; e < end; e += 256)
        atomicAdd(&hist[binned[e].x & (BR - 1)], 1);
    __syncthreads();
    int v0 = (2 * t < BR) ? hist[2 * t] : 0;
    int v1 = (2 * t + 1 < BR) ? hist[2 * t + 1] : 0;
    psum[t] = v0 + v1;
    __syncthreads();
    for (int off = 1; off < 256; off <<= 1) {
        int x = (t >= off) ? psum[t - off] : 0;
        __syncthreads();
        psum[t] += x;
        __syncthreads();
    }
    int ep = psum[t] - (v0 + v1);
    if (2 * t < BR) scn[2 * t] = ep;
    if (2 * t + 1 < BR) scn[2 * t + 1] = ep + v0;
    __syncthreads();
    for (int r = t; r < BR; r += 256) {
        int row = row0 + r;
        if (row < nrows) ptr[row] = beg + scn[r];
        hist[r] = 0;
    }
    if (j == 0 && t == 0) ptr[nrows] = total;
    __syncthreads();
    for (int e = beg + t; e < end; e += 256) {
        int2 rec = binned[e];
        int rl = rec.x & (BR - 1);
        int pos = beg + scn[rl] + atomicAdd(&hist[rl], 1);
        cs[pos] = make_int2(((unsigned)rec.x) >> sh, rec.y);
    }
}

// ======================= f32 -> bf16 array convert =======================
__global__ void k_tobf(const float* __restrict__ in, unsigned short* __restrict__ out, int n8)
{
    int i = blockIdx.x * 256 + threadIdx.x;
    if (i >= n8) return;
    float4 a = reinterpret_cast<const float4*>(in)[2 * i];
    float4 c = reinterpret_cast<const float4*>(in)[2 * i + 1];
    uint4 o;
    o.x = (unsigned)f2bf(a.x) | ((unsigned)f2bf(a.y) << 16);
    o.y = (unsigned)f2bf(a.z) | ((unsigned)f2bf(a.w) << 16);
    o.z = (unsigned)f2bf(c.x) | ((unsigned)f2bf(c.y) << 16);
    o.w = (unsigned)f2bf(c.z) | ((unsigned)f2bf(c.w) << 16);
    reinterpret_cast<uint4*>(out)[i] = o;
}

// ===== batched gather core: 16 edges per step, coalesced pairs + shfl broadcast =====
// 16-lane group (lanes lr=0..15, wave-lane base gb), row slice = 8 bf16 at 8*lr.
// Partial batches padded with (idx=0, v=0): reads row 0 (L1-hot), adds 0.
__device__ __forceinline__ void gather16(const int2* __restrict__ pairs,
                                         const unsigned short* __restrict__ src,
                                         int beg, int end, int lr, int gb,
                                         float* __restrict__ acc)
{
    for (int base = beg; base < end; base += 16) {
        int2 pl = make_int2(0, 0);
        if (base + lr < end) pl = pairs[base + lr];
        int   idx[16];
        float vv[16];
        #pragma unroll
        for (int e = 0; e < 16; ++e) {
            idx[e] = __shfl(pl.x, gb + e, 64);
            vv[e]  = __int_as_float(__shfl(pl.y, gb + e, 64));
        }
        v8s s[8];
        #pragma unroll
        for (int e = 0; e < 8; ++e)
            s[e] = *reinterpret_cast<const v8s*>(src + (long long)idx[e] * DIM + 8 * lr);
        #pragma unroll
        for (int e = 0; e < 8; ++e) {
            #pragma unroll
            for (int k = 0; k < 8; ++k)
                acc[k] += vv[e] * bf2f(s[e][k]);
        }
        #pragma unroll
        for (int e = 0; e < 8; ++e)
            s[e] = *reinterpret_cast<const v8s*>(src + (long long)idx[8 + e] * DIM + 8 * lr);
        #pragma unroll
        for (int e = 0; e < 8; ++e) {
            #pragma unroll
            for (int k = 0; k < 8; ++k)
                acc[k] += vv[8 + e] * bf2f(s[e][k]);
        }
    }
}

// ======================= gather SpMM, bf16 source (16 lanes/row) ==========
__global__ __launch_bounds__(256) void k_spmm_bf(const int* __restrict__ ptr, const int2* __restrict__ pairs,
                                                 const unsigned short* __restrict__ src,
                                                 float* __restrict__ dst, int nrows)
{
    int r = blockIdx.x * 16 + (threadIdx.x >> 4);
    if (r >= nrows) return;
    int lr = threadIdx.x & 15;
    int gb = (threadIdx.x & 63) & ~15;
    int beg = ptr[r], end = ptr[r + 1];
    float acc[8];
    #pragma unroll
    for (int k = 0; k < 8; ++k) acc[k] = 0.f;
    gather16(pairs, src, beg, end, lr, gb, acc);
    float4 o0, o1;
    o0.x = acc[0]; o0.y = acc[1]; o0.z = acc[2]; o0.w = acc[3];
    o1.x = acc[4]; o1.y = acc[5]; o1.z = acc[6]; o1.w = acc[7];
    float* dp = dst + (long long)r * DIM + 8 * lr;
    *reinterpret_cast<float4*>(dp) = o0;
    *reinterpret_cast<float4*>(dp + 4) = o1;
}

// ======================= gather SpMM f32 (fallback paths) =======================
__global__ __launch_bounds__(256) void k_spmm4(const int* __restrict__ ptr, const int2* __restrict__ pairs,
                                               const float* __restrict__ src, float* __restrict__ dst, int nrows)
{
    int r = blockIdx.x * 8 + (threadIdx.x >> 5);
    if (r >= nrows) return;
    int l = threadIdx.x & 31;
    int beg = ptr[r], end = ptr[r + 1];
    float4 a0 = {0.f, 0.f, 0.f, 0.f}, a1 = {0.f, 0.f, 0.f, 0.f};
    int j = beg;
    for (; j + 1 < end; j += 2) {
        int2 p0 = pairs[j], p1 = pairs[j + 1];
        float v0 = __int_as_float(p0.y), v1 = __int_as_float(p1.y);
        float4 s0 = *reinterpret_cast<const float4*>(src + (long long)p0.x * DIM + 4 * l);
        float4 s1 = *reinterpret_cast<const float4*>(src + (long long)p1.x * DIM + 4 * l);
        a0.x += v0 * s0.x; a0.y += v0 * s0.y; a0.z += v0 * s0.z; a0.w += v0 * s0.w;
        a1.x += v1 * s1.x; a1.y += v1 * s1.y; a1.z += v1 * s1.z; a1.w += v1 * s1.w;
    }
    if (j < end) {
        int2 p0 = pairs[j];
        float v0 = __int_as_float(p0.y);
        float4 s0 = *reinterpret_cast<const float4*>(src + (long long)p0.x * DIM + 4 * l);
        a0.x += v0 * s0.x; a0.y += v0 * s0.y; a0.z += v0 * s0.z; a0.w += v0 * s0.w;
    }
    a0.x += a1.x; a0.y += a1.y; a0.z += a1.z; a0.w += a1.w;
    *reinterpret_cast<float4*>(dst + (long long)r * DIM + 4 * l) = a0;
}

// ======================= Bsw pack: W[c][k] f32 -> bf16 MFMA-B layout =======================
__global__ void k_bsw(const float* __restrict__ W, unsigned short* __restrict__ Bsw)
{
    int i = blockIdx.x * 256 + threadIdx.x;      // 0..32767
    int kt = i >> 12;
    int rem = i & 4095;
    int c = rem >> 5;
    int kk = rem & 31;
    Bsw[i] = f2bf(W[c * 256 + kt * 32 + kk]);
}

// ======================= FUSED: u-side gather SpMM + gate + bf16 MFMA linear ==========
// 128 thr = 2 waves; each wave owns 16 users + a private 8.4 KB cat slice.
// Phase 1: 16-edge shfl-batched gather of node_msg + ue gate -> bf16 cat.
// Phase 2: 64 MFMA linear. Writes msg (f32) + msg_bf (bf16).
__global__ __launch_bounds__(128) void k_fused(const int* __restrict__ ptr,
                                               const int2* __restrict__ pairs,
                                               const unsigned short* __restrict__ itbf,
                                               const float* __restrict__ uef32,
                                               const unsigned short* __restrict__ uebf,
                                               int use_uebf,
                                               const unsigned short* __restrict__ Bsw,
                                               const float* __restrict__ b,
                                               float* __restrict__ msg,
                                               unsigned short* __restrict__ msg_bf, int nu)
{
    __shared__ unsigned short cat[2][16 * 264];  // 16896 B
    int tid = threadIdx.x;
    int w = tid >> 6, l = tid & 63;
    int lr = l & 15, hi = l >> 4;
    int gb = l & ~15;
    int d = lr * 8;
    int uw = blockIdx.x * 32 + w * 16;
    unsigned short* mycat = &cat[w][0];

    #pragma unroll
    for (int p = 0; p < 4; ++p) {
        int ur = p * 4 + hi;                     // 0..15
        int u = uw + ur;
        float acc[8];
        #pragma unroll
        for (int k = 0; k < 8; ++k) acc[k] = 0.f;
        float uev[8];
        #pragma unroll
        for (int k = 0; k < 8; ++k) uev[k] = 0.f;
        if (u < nu) {
            if (use_uebf) {
                uint4 up = *reinterpret_cast<const uint4*>(uebf + (long long)u * DIM + d);
                uev[0] = bf2f((short)(up.x & 0xffff)); uev[1] = bf2f((short)(up.x >> 16));
                uev[2] = bf2f((short)(up.y & 0xffff)); uev[3] = bf2f((short)(up.y >> 16));
                uev[4] = bf2f((short)(up.z & 0xffff)); uev[5] = bf2f((short)(up.z >> 16));
                uev[6] = bf2f((short)(up.w & 0xffff)); uev[7] = bf2f((short)(up.w >> 16));
            } else {
                float4 ue0 = *reinterpret_cast<const float4*>(uef32 + (long long)u * DIM + d);
                float4 ue1 = *reinterpret_cast<const float4*>(uef32 + (long long)u * DIM + d + 4);
                uev[0] = ue0.x; uev[1] = ue0.y; uev[2] = ue0.z; uev[3] = ue0.w;
                uev[4] = ue1.x; uev[5] = ue1.y; uev[6] = ue1.z; uev[7] = ue1.w;
            }
            int beg = ptr[u], end = ptr[u + 1];
            gather16(pairs, itbf, beg, end, lr, gb, acc);
        }
        uint4 nmp, gp;
        nmp.x = (unsigned)f2bf(acc[0]) | ((unsigned)f2bf(acc[1]) << 16);
        nmp.y = (unsigned)f2bf(acc[2]) | ((unsigned)f2bf(acc[3]) << 16);
        nmp.z = (unsigned)f2bf(acc[4]) | ((unsigned)f2bf(acc[5]) << 16);
        nmp.w = (unsigned)f2bf(acc[6]) | ((unsigned)f2bf(acc[7]) << 16);
        gp.x = (unsigned)f2bf(acc[0] * uev[0]) | ((unsigned)f2bf(acc[1] * uev[1]) << 16);
        gp.y = (unsigned)f2bf(acc[2] * uev[2]) | ((unsigned)f2bf(acc[3] * uev[3]) << 16);
        gp.z = (unsigned)f2bf(acc[4] * uev[4]) | ((unsigned)f2bf(acc[5] * uev[5]) << 16);
        gp.w = (unsigned)f2bf(acc[6] * uev[6]) | ((unsigned)f2bf(acc[7] * uev[7]) << 16);
        *reinterpret_cast<uint4*>(mycat + ur * 264 + d) = nmp;
        *reinterpret_cast<uint4*>(mycat + ur * 264 + 128 + d) = gp;
    }
    __syncthreads();

    v4f facc[8];
    #pragma unroll
    for (int ct = 0; ct < 8; ++ct) facc[ct] = (v4f){0.f, 0.f, 0.f, 0.f};
    const unsigned short* arow = mycat + lr * 264;
    for (int kt = 0; kt < 8; ++kt) {
        v8s a = *reinterpret_cast<const v8s*>(arow + kt * 32 + hi * 8);
        #pragma unroll
        for (int ct = 0; ct < 8; ++ct) {
            v8s bb = *reinterpret_cast<const v8s*>(Bsw + kt * 4096 + (ct * 16 + lr) * 32 + hi * 8);
            facc[ct] = __builtin_amdgcn_mfma_f32_16x16x32_bf16(a, bb, facc[ct], 0, 0, 0);
        }
    }

    int ub = uw + hi * 4;
    #pragma unroll
    for (int ct = 0; ct < 8; ++ct) {
        float bc = b[ct * 16 + lr];
        #pragma unroll
        for (int j = 0; j < 4; ++j) {
            int u = ub + j;
            if (u < nu) {
                float val = facc[ct][j] + bc;
                long long p = (long long)u * DIM + ct * 16 + lr;
                msg[p] = val;
                msg_bf[p] = f2bf(val);
            }
        }
    }
}

// ======================= unfused linear (R9 fallback) =======================
__global__ __launch_bounds__(256) void k_msg5(const float* __restrict__ nm_in,
                                              const float* __restrict__ ue,
                                              const unsigned short* __restrict__ Bsw,
                                              const float* __restrict__ b,
                                              float* __restrict__ msg,
                                              unsigned short* __restrict__ msg_bf, int nu)
{
    __shared__ unsigned short cat[64 * 264];
    int tid = threadIdx.x;
    int u0 = blockIdx.x * 64;

    for (int idx = tid; idx < 2048; idx += 256) {
        int u = idx >> 5, d4 = idx & 31;
        float4 nm4 = make_float4(0.f, 0.f, 0.f, 0.f);
        float4 ue4 = make_float4(0.f, 0.f, 0.f, 0.f);
        if (u0 + u < nu) {
            long long p = (long long)(u0 + u) * DIM + d4 * 4;
            nm4 = *reinterpret_cast<const float4*>(nm_in + p);
            ue4 = *reinterpret_cast<const float4*>(ue + p);
        }
        unsigned short* row = cat + u * 264;
        uint2 nmp, gp;
        nmp.x = (unsigned)f2bf(nm4.x) | ((unsigned)f2bf(nm4.y) << 16);
        nmp.y = (unsigned)f2bf(nm4.z) | ((unsigned)f2bf(nm4.w) << 16);
        gp.x  = (unsigned)f2bf(nm4.x * ue4.x) | ((unsigned)f2bf(nm4.y * ue4.y) << 16);
        gp.y  = (unsigned)f2bf(nm4.z * ue4.z) | ((unsigned)f2bf(nm4.w * ue4.w) << 16);
        *reinterpret_cast<uint2*>(row + d4 * 4) = nmp;
        *reinterpret_cast<uint2*>(row + 128 + d4 * 4) = gp;
    }
    __syncthreads();

    int l = tid & 63, w = tid >> 6;
    int lr = l & 15, hi = l >> 4;
    v4f acc[8];
    #pragma unroll
    for (int ct = 0; ct < 8; ++ct) acc[ct] = (v4f){0.f, 0.f, 0.f, 0.f};

    const unsigned short* arow = cat + (w * 16 + lr) * 264;
    for (int kt = 0; kt < 8; ++kt) {
        v8s a = *reinterpret_cast<const v8s*>(arow + kt * 32 + hi * 8);
        #pragma unroll
        for (int ct = 0; ct < 8; ++ct) {
            v8s bb = *reinterpret_cast<const v8s*>(Bsw + kt * 4096 + (ct * 16 + lr) * 32 + hi * 8);
            acc[ct] = __builtin_amdgcn_mfma_f32_16x16x32_bf16(a, bb, acc[ct], 0, 0, 0);
        }
    }

    int ub = u0 + w * 16 + hi * 4;
    #pragma unroll
    for (int ct = 0; ct < 8; ++ct) {
        float bc = b[ct * 16 + lr];
        #pragma unroll
        for (int j = 0; j < 4; ++j) {
            int u = ub + j;
            if (u < nu) {
                float val = acc[ct][j] + bc;
                long long p = (long long)u * DIM + ct * 16 + lr;
                msg[p] = val;
                msg_bf[p] = f2bf(val);
            }
        }
    }
}

// ======================= f32 linear (R5 fallback path) =======================
__global__ void k_wt(const float* __restrict__ W, float* __restrict__ Wt)
{
    int t = blockIdx.x * 256 + threadIdx.x;
    int k = t >> 7;
    int c = t & 127;
    Wt[t] = W[c * 256 + k];
}

#define UPB 32
#define CATP 260

__global__ __launch_bounds__(256) void k_msg4(const float* __restrict__ nm_in,
                                              const float* __restrict__ ue,
                                              const float* __restrict__ Wt,
                                              const float* __restrict__ b,
                                              float* __restrict__ msg, int nu)
{
    __shared__ float cat[UPB * CATP];
    int tid = threadIdx.x;
    int u0 = blockIdx.x * UPB;
    for (int idx = tid; idx < UPB * DIM; idx += 256) {
        int u = idx >> 7, d = idx & 127;
        float nm = 0.f, g = 0.f;
        if (u0 + u < nu) {
            long long p = (long long)(u0 + u) * DIM + d;
            nm = nm_in[p];
            g = nm * ue[p];
        }
        cat[u * CATP + d] = nm;
        cat[u * CATP + DIM + d] = g;
    }
    __syncthreads();

    int tc = tid & 31;
    int tu = tid >> 5;
    float acc[4][4];
    #pragma unroll
    for (int r = 0; r < 4; ++r)
        #pragma unroll
        for (int c = 0; c < 4; ++c) acc[r][c] = 0.f;

    const float* cbase = &cat[(tu * 4) * CATP];
    for (int k4 = 0; k4 < 64; ++k4) {
        float4 w[4];
        #pragma unroll
        for (int kk = 0; kk < 4; ++kk)
            w[kk] = *reinterpret_cast<const float4*>(Wt + (k4 * 4 + kk) * DIM + tc * 4);
        #pragma unroll
        for (int r = 0; r < 4; ++r) {
            float4 a = *reinterpret_cast<const float4*>(cbase + r * CATP + k4 * 4);
            acc[r][0] += a.x * w[0].x + a.y * w[1].x + a.z * w[2].x + a.w * w[3].x;
            acc[r][1] += a.x * w[0].y + a.y * w[1].y + a.z * w[2].y + a.w * w[3].y;
            acc[r][2] += a.x * w[0].z + a.y * w[1].z + a.z * w[2].z + a.w * w[3].z;
            acc[r][3] += a.x * w[0].w + a.y * w[1].w + a.z * w[2].w + a.w * w[3].w;
        }
    }

    float4 bb = *reinterpret_cast<const float4*>(b + tc * 4);
    #pragma unroll
    for (int r = 0; r < 4; ++r) {
        int u = u0 + tu * 4 + r;
        if (u < nu) {
            float4 o;
            o.x = acc[r][0] + bb.x; o.y = acc[r][1] + bb.y;
            o.z = acc[r][2] + bb.z; o.w = acc[r][3] + bb.w;
            *reinterpret_cast<float4*>(msg + (long long)u * DIM + tc * 4) = o;
        }
    }
}

// ======================= fallback: direct-scatter CSR build =======================

__global__ void k_count(const int* __restrict__ rows, const int* __restrict__ cols,
                        int* __restrict__ cnt_u, int* __restrict__ cnt_i, int nnz4, int nnz)
{
    int i = blockIdx.x * blockDim.x + threadIdx.x;
    int stride = gridDim.x * blockDim.x;
    for (int e4 = i; e4 < nnz4; e4 += stride) {
        int4 r = reinterpret_cast<const int4*>(rows)[e4];
        int4 c = reinterpret_cast<const int4*>(cols)[e4];
        atomicAdd(&cnt_u[r.x], 1); atomicAdd(&cnt_u[r.y], 1);
        atomicAdd(&cnt_u[r.z], 1); atomicAdd(&cnt_u[r.w], 1);
        atomicAdd(&cnt_i[c.x], 1); atomicAdd(&cnt_i[c.y], 1);
        atomicAdd(&cnt_i[c.z], 1); atomicAdd(&cnt_i[c.w], 1);
    }
    for (int e = nnz4 * 4 + i; e < nnz; e += stride) {
        atomicAdd(&cnt_u[rows[e]], 1);
        atomicAdd(&cnt_i[cols[e]], 1);
    }
}

__global__ void k_scan1(const int* __restrict__ cnt, int* __restrict__ ptr,
                        int* __restrict__ partial, int n)
{
    __shared__ int s[256];
    int i = blockIdx.x * 256 + threadIdx.x;
    int v = (i < n) ? cnt[i] : 0;
    s[threadIdx.x] = v;
    __syncthreads();
    for (int off = 1; off < 256; off <<= 1) {
        int x = (threadIdx.x >= off) ? s[threadIdx.x - off] : 0;
        __syncthreads();
        s[threadIdx.x] += x;
        __syncthreads();
    }
    if (i < n) ptr[i] = s[threadIdx.x] - v;
    if (threadIdx.x == 255) partial[blockIdx.x] = s[255];
}

__global__ void k_scan2(int* __restrict__ partial, int n)
{
    __shared__ int s[512];
    int v = (threadIdx.x < (unsigned)n) ? partial[threadIdx.x] : 0;
    s[threadIdx.x] = v;
    __syncthreads();
    for (int off = 1; off < 512; off <<= 1) {
        int x = (threadIdx.x >= off) ? s[threadIdx.x - off] : 0;
        __syncthreads();
        s[threadIdx.x] += x;
        __syncthreads();
    }
    if (threadIdx.x < (unsigned)n) partial[threadIdx.x] = s[threadIdx.x] - v;
}

__global__ void k_scan3(int* __restrict__ ptr, const int* __restrict__ partial,
                        int* __restrict__ woff, int n, int total)
{
    int i = blockIdx.x * 256 + threadIdx.x;
    if (i < n) {
        int p = ptr[i] + partial[blockIdx.x];
        ptr[i] = p;
        woff[i] = p;
        if (i == n - 1) ptr[n] = total;
    }
}

__global__ void k_edge_scatter(const int* __restrict__ rows, const int* __restrict__ cols,
                               const float* __restrict__ vals,
                               int* __restrict__ woff_u, int* __restrict__ woff_i,
                               int2* __restrict__ cs_u, int2* __restrict__ cs_i,
                               int nnz4, int nnz)
{
    int i = blockIdx.x * blockDim.x + threadIdx.x;
    int stride = gridDim.x * blockDim.x;
    for (int e4 = i; e4 < nnz4; e4 += stride) {
        int4 r = reinterpret_cast<const int4*>(rows)[e4];
        int4 c = reinterpret_cast<const int4*>(cols)[e4];
        float4 v = reinterpret_cast<const float4*>(vals)[e4];
        int pu, pi;
        pu = atomicAdd(&woff_u[r.x], 1); cs_u[pu] = make_int2(c.x, __float_as_int(v.x));
        pi = atomicAdd(&woff_i[c.x], 1); cs_i[pi] = make_int2(r.x, __float_as_int(v.x));
        pu = atomicAdd(&woff_u[r.y], 1); cs_u[pu] = make_int2(c.y, __float_as_int(v.y));
        pi = atomicAdd(&woff_i[c.y], 1); cs_i[pi] = make_int2(r.y, __float_as_int(v.y));
        pu = atomicAdd(&woff_u[r.z], 1); cs_u[pu] = make_int2(c.z, __float_as_int(v.z));
        pi = atomicAdd(&woff_i[c.z], 1); cs_i[pi] = make_int2(r.z, __float_as_int(v.z));
        pu = atomicAdd(&woff_u[r.w], 1); cs_u[pu] = make_int2(c.w, __float_as_int(v.w));
        pi = atomicAdd(&woff_i[c.w], 1); cs_i[pi] = make_int2(r.w, __float_as_int(v.w));
    }
    for (int e = nnz4 * 4 + i; e < nnz; e += stride) {
        int r = rows[e], c = cols[e];
        float v = vals[e];
        int pu = atomicAdd(&woff_u[r], 1); cs_u[pu] = make_int2(c, __float_as_int(v));
        int pi = atomicAdd(&woff_i[c], 1); cs_i[pi] = make_int2(r, __float_as_int(v));
    }
}

// ======================= fallback: atomic path =======================

__global__ void k_scatter(const int* __restrict__ didx, const int* __restrict__ sidx,
                          const float* __restrict__ vals, const float* __restrict__ src,
                          float* __restrict__ dst, long long nnz)
{
    long long t = (long long)blockIdx.x * blockDim.x + threadIdx.x;
    long long total = nnz * 32;
    if (t >= total) return;
    long long e = t >> 5;
    int d = (int)(t & 31) * 4;
    int si = sidx[e];
    int di = didx[e];
    float v = vals[e];
    const float4 s = *reinterpret_cast<const float4*>(src + (long long)si * DIM + d);
    float* p = dst + (long long)di * DIM + d;
    atomicAdd(p + 0, v * s.x);
    atomicAdd(p + 1, v * s.y);
    atomicAdd(p + 2, v * s.z);
    atomicAdd(p + 3, v * s.w);
}

__global__ void k_msg_simple(const float* __restrict__ user_emb, const float* __restrict__ W,
                             const float* __restrict__ b, float* __restrict__ msg)
{
    __shared__ float cat[2 * DIM];
    int u = blockIdx.x;
    int t = threadIdx.x;
    long long base = (long long)u * DIM;
    float nm = msg[base + t];
    float ue = user_emb[base + t];
    cat[t] = nm;
    cat[DIM + t] = nm * ue;
    __syncthreads();
    float acc = b[t];
    const float4* Wr = reinterpret_cast<const float4*>(W + (long long)t * 2 * DIM);
    const float4* c4 = reinterpret_cast<const float4*>(cat);
    #pragma unroll
    for (int k = 0; k < 2 * DIM / 4; ++k) {
        float4 w = Wr[k];
        float4 c = c4[k];
        acc += w.x * c.x + w.y * c.y + w.z * c.z + w.w * c.w;
    }
    msg[base + t] = acc;
}

// ======================= launch =======================

extern "C" void kernel_launch(void* const* d_in, const int* in_sizes, int n_in,
                              void* d_out, int out_size, void* d_ws, size_t ws_size,
                              hipStream_t stream) {
    const float* user_emb = (const float*)d_in[0];
    const float* item_emb = (const float*)d_in[1];
    const int*   rows     = (const int*)d_in[2];
    const int*   cols     = (const int*)d_in[3];
    const float* vals     = (const float*)d_in[4];
    const float* W        = (const float*)d_in[5];
    const float* b        = (const float*)d_in[6];

    int nu = in_sizes[0] / DIM;
    int ni = in_sizes[1] / DIM;
    int nnz = in_sizes[2];

    float* norm_emb = (float*)d_out;                              // [ni, DIM]
    float* msg      = (float*)d_out + (long long)ni * DIM;        // [nu, DIM]

    auto align256 = [](size_t x) { return (x + 255) & ~(size_t)255; };

    int shu = 0; while ((((long long)nu + (1LL << shu) - 1) >> shu) > 256) shu++;
    int shi = 0; while ((((long long)ni + (1LL << shi) - 1) >> shi) > 256) shi++;
    int nbu = (int)(((long long)nu + (1LL << shu) - 1) >> shu);
    int nbi = (int)(((long long)ni + (1LL << shi) - 1) >> shi);
    int chunk = (((nnz + NB - 1) / NB) + 3) & ~3;

    // ---- shared base layout (binned paths) ----
    size_t off = 0;
    size_t o_bu    = off; off = align256(off + (size_t)nnz * 8);
    size_t o_bi    = off; off = align256(off + (size_t)nnz * 8);
    size_t o_csu   = off; off = align256(off + (size_t)nnz * 8);
    size_t o_Mu    = off; off = align256(off + (size_t)NB * nbu * 4);
    size_t o_Mi    = off; off = align256(off + (size_t)NB * nbi * 4);
    size_t o_totu  = off; off = align256(off + (size_t)nbu * 4);
    size_t o_toti  = off; off = align256(off + (size_t)nbi * 4);
    size_t o_baseu = off; off = align256(off + (size_t)(nbu + 1) * 4);
    size_t o_basei = off; off = align256(off + (size_t)(nbi + 1) * 4);
    size_t o_ptru  = off; off = align256(off + (size_t)(nu + 1) * 4);
    size_t o_ptri  = off; off = align256(off + (size_t)(ni + 1) * 4);
    size_t o_bsw   = off; off = align256(off + (size_t)32768 * 2);
    size_t need_base = off;

    size_t itbf_need  = (size_t)ni * DIM * 2;
    size_t msgbf_need = (size_t)nu * DIM * 2;
    size_t uebf_need  = (size_t)nu * DIM * 2;
    bool alias_it = (o_csu - o_bi) >= itbf_need;   // itbf in bi (dead after binC_i)

    // fused layout: msgbf appended (cs_u stays live during fused kernel)
    size_t need_fused = need_base;
    size_t o_msgbf_f = need_fused; need_fused = align256(need_fused + msgbf_need);
    size_t o_itbf_f;
    if (alias_it) o_itbf_f = o_bi;
    else { o_itbf_f = need_fused; need_fused = align256(need_fused + itbf_need); }
    // optional bf16 user_emb appended on top
    size_t o_uebf = need_fused;
    size_t need_fused_ue = align256(need_fused + uebf_need);

    // R9 (unfused) layout: msgbf may alias bi+csu (dead after spmm_u)
    size_t need_r9 = need_base;
    bool alias_msg = (o_Mu - o_bi) >= msgbf_need;
    size_t o_itbf_9, o_msgbf_9;
    if (alias_it) o_itbf_9 = o_bi;
    else { o_itbf_9 = need_r9; need_r9 = align256(need_r9 + itbf_need); }
    if (alias_msg) o_msgbf_9 = o_bi;
    else { o_msgbf_9 = need_r9; need_r9 = align256(need_r9 + msgbf_need); }

    bool pack_ok = ((long long)ni < (1LL << (31 - shu))) && ((long long)nu < (1LL << (31 - shi)))
                   && (shu <= 9) && (shi <= 9);

    // ---- R5-path layout ----
    off = 0;
    size_t o_cs_u   = off; off = align256(off + (size_t)nnz * 8);
    size_t o_cs_i   = off; off = align256(off + (size_t)nnz * 8);
    size_t o_ptr_u  = off; off = align256(off + (size_t)(nu + 1) * 4);
    size_t o_ptr_i  = off; off = align256(off + (size_t)(ni + 1) * 4);
    size_t o_woff_u = off; off = align256(off + (size_t)nu * 4);
    size_t o_woff_i = off; off = align256(off + (size_t)ni * 4);
    size_t o_part_u = off; off = align256(off + 512 * 4);
    size_t o_part_i = off; off = align256(off + 512 * 4);
    size_t o_wt2    = off; off = align256(off + (size_t)256 * DIM * 4);
    size_t need_r5 = off;

    int npb_u = (nu + 255) / 256;
    int npb_i = (ni + 255) / 256;

    char* ws = (char*)d_ws;

    if (pack_ok && (ws_size >= need_fused || ws_size >= need_r9)) {
        bool fused   = (ws_size >= need_fused);
        bool use_ue  = fused && (ws_size >= need_fused_ue);
        int2* bu     = (int2*)(ws + o_bu);
        int2* bi     = (int2*)(ws + o_bi);
        int2* cs_u   = (int2*)(ws + o_csu);
        int2* cs_i   = (int2*)(ws + o_bu);     // alias: binned_u dead after binC_u
        int*  Mu     = (int*)(ws + o_Mu);
        int*  Mi     = (int*)(ws + o_Mi);
        int*  totu   = (int*)(ws + o_totu);
        int*  toti   = (int*)(ws + o_toti);
        int*  baseu  = (int*)(ws + o_baseu);
        int*  basei  = (int*)(ws + o_basei);
        int*  ptr_u  = (int*)(ws + o_ptru);
        int*  ptr_i  = (int*)(ws + o_ptri);
        unsigned short* bsw   = (unsigned short*)(ws + o_bsw);
        unsigned short* itbf  = (unsigned short*)(ws + (fused ? o_itbf_f : o_itbf_9));
        unsigned short* msgbf = (unsigned short*)(ws + (fused ? o_msgbf_f : o_msgbf_9));
        unsigned short* uebf  = (unsigned short*)(ws + o_uebf);

        k_binA<<<NB, 256, 0, stream>>>(rows, cols, Mu, Mi, nnz, chunk, nbu, nbi, shu, shi);
        k_bsw<<<128, 256, 0, stream>>>(W, bsw);
        if (use_ue) {
            int n8u = nu * DIM / 8;
            k_tobf<<<(n8u + 255) / 256, 256, 0, stream>>>(user_emb, uebf, n8u);
        }
        k_binS1<<<nbu, 256, 0, stream>>>(Mu, totu, nbu, NB);
        k_binS1<<<nbi, 256, 0, stream>>>(Mi, toti, nbi, NB);
        k_binS2<<<1, 256, 0, stream>>>(totu, baseu, nbu);
        k_binS2<<<1, 256, 0, stream>>>(toti, basei, nbi);
        k_binB<<<NB, 256, 0, stream>>>(rows, cols, vals, Mu, Mi, baseu, basei,
                                       bu, bi, nnz, chunk, nbu, nbi, shu, shi);
        k_binC<<<nbu, 256, 0, stream>>>(bu, baseu, ptr_u, cs_u, nu, shu, nnz);
        k_binC<<<nbi, 256, 0, stream>>>(bi, basei, ptr_i, cs_i, ni, shi, nnz);

        int n8i = ni * DIM / 8;
        k_tobf<<<(n8i + 255) / 256, 256, 0, stream>>>(item_emb, itbf, n8i);

        if (fused) {
            k_fused<<<(nu + 31) / 32, 128, 0, stream>>>(ptr_u, cs_u, itbf, user_emb,
                                                        uebf, use_ue ? 1 : 0,
                                                        bsw, b, msg, msgbf, nu);
        } else {
            k_spmm_bf<<<(nu + 15) / 16, 256, 0, stream>>>(ptr_u, cs_u, itbf, msg, nu);
            k_msg5<<<(nu + 63) / 64, 256, 0, stream>>>(msg, user_emb, bsw, b, msg, msgbf, nu);
        }
        // norm_emb = H^T @ msg(bf16)
        k_spmm_bf<<<(ni + 15) / 16, 256, 0, stream>>>(ptr_i, cs_i, msgbf, norm_emb, ni);
    } else if (ws_size >= need_r5 && npb_u <= 512 && npb_i <= 512) {
        int2*  cs_u   = (int2*)(ws + o_cs_u);
        int2*  cs_i   = (int2*)(ws + o_cs_i);
        int*   ptr_u  = (int*)(ws + o_ptr_u);
        int*   ptr_i  = (int*)(ws + o_ptr_i);
        int*   woff_u = (int*)(ws + o_woff_u);
        int*   woff_i = (int*)(ws + o_woff_i);
        int*   part_u = (int*)(ws + o_part_u);
        int*   part_i = (int*)(ws + o_part_i);
        float* wt     = (float*)(ws + o_wt2);

        hipMemsetAsync(woff_u, 0, (size_t)nu * 4, stream);
        hipMemsetAsync(woff_i, 0, (size_t)ni * 4, stream);

        int nnz4 = nnz / 4;
        int gs = 1024;
        k_count<<<gs, 256, 0, stream>>>(rows, cols, woff_u, woff_i, nnz4, nnz);
        k_wt<<<(256 * DIM) / 256, 256, 0, stream>>>(W, wt);

        k_scan1<<<npb_u, 256, 0, stream>>>(woff_u, ptr_u, part_u, nu);
        k_scan1<<<npb_i, 256, 0, stream>>>(woff_i, ptr_i, part_i, ni);
        k_scan2<<<1, 512, 0, stream>>>(part_u, npb_u);
        k_scan2<<<1, 512, 0, stream>>>(part_i, npb_i);
        k_scan3<<<npb_u, 256, 0, stream>>>(ptr_u, part_u, woff_u, nu, nnz);
        k_scan3<<<npb_i, 256, 0, stream>>>(ptr_i, part_i, woff_i, ni, nnz);

        k_edge_scatter<<<gs, 256, 0, stream>>>(rows, cols, vals, woff_u, woff_i,
                                               cs_u, cs_i, nnz4, nnz);

        k_spmm4<<<(nu + 7) / 8, 256, 0, stream>>>(ptr_u, cs_u, item_emb, msg, nu);
        k_msg4<<<(nu + UPB - 1) / UPB, 256, 0, stream>>>(msg, user_emb, wt, b, msg, nu);
        k_spmm4<<<(ni + 7) / 8, 256, 0, stream>>>(ptr_i, cs_i, msg, norm_emb, ni);
    } else {
        hipMemsetAsync(d_out, 0, (size_t)out_size * sizeof(float), stream);
        long long tot = (long long)nnz * 32;
        int blk = 256;
        long long nblk = (tot + blk - 1) / blk;
        k_scatter<<<(int)nblk, blk, 0, stream>>>(rows, cols, vals, item_emb, msg, nnz);
        k_msg_simple<<<nu, DIM, 0, stream>>>(user_emb, W, b, msg);
        k_scatter<<<(int)nblk, blk, 0, stream>>>(cols, rows, vals, msg, norm_emb, nnz);
    }
}

// Round 14
// 268.559 us; speedup vs baseline: 1.0636x; 1.0636x over previous
//
#include <hip/hip_runtime.h>

#define DIM 128
#define NB 512            // binning grid blocks (pass A/B)

typedef short v8s __attribute__((ext_vector_type(8)));
typedef float v4f __attribute__((ext_vector_type(4)));

__device__ __forceinline__ unsigned short f2bf(float f) {
    unsigned int x = __float_as_uint(f);
    unsigned int r = ((x >> 16) & 1u) + 0x7fffu;
    return (unsigned short)((x + r) >> 16);
}
__device__ __forceinline__ float bf2f(short s) {
    return __uint_as_float(((unsigned)(unsigned short)s) << 16);
}

// ======================= binned CSR build (no global atomics) =======================

__global__ __launch_bounds__(256) void k_binA(const int* __restrict__ rows, const int* __restrict__ cols,
                                              int* __restrict__ Mu, int* __restrict__ Mi,
                                              int nnz, int chunk, int nbu, int nbi, int shu, int shi)
{
    __shared__ int hu[256], hi[256];
    int k = blockIdx.x, t = threadIdx.x;
    for (int j = t; j < nbu; j += 256) hu[j] = 0;
    for (int j = t; j < nbi; j += 256) hi[j] = 0;
    __syncthreads();
    int beg = k * chunk, end = min(beg + chunk, nnz);
    if (beg < end) {
        int beg4 = beg >> 2, end4 = end >> 2;
        for (int e4 = beg4 + t; e4 < end4; e4 += 256) {
            int4 r = reinterpret_cast<const int4*>(rows)[e4];
            int4 c = reinterpret_cast<const int4*>(cols)[e4];
            atomicAdd(&hu[r.x >> shu], 1); atomicAdd(&hu[r.y >> shu], 1);
            atomicAdd(&hu[r.z >> shu], 1); atomicAdd(&hu[r.w >> shu], 1);
            atomicAdd(&hi[c.x >> shi], 1); atomicAdd(&hi[c.y >> shi], 1);
            atomicAdd(&hi[c.z >> shi], 1); atomicAdd(&hi[c.w >> shi], 1);
        }
        for (int e = (end4 << 2) + t; e < end; e += 256) {
            atomicAdd(&hu[rows[e] >> shu], 1);
            atomicAdd(&hi[cols[e] >> shi], 1);
        }
    }
    __syncthreads();
    for (int j = t; j < nbu; j += 256) Mu[k * nbu + j] = hu[j];
    for (int j = t; j < nbi; j += 256) Mi[k * nbi + j] = hi[j];
}

__global__ __launch_bounds__(256) void k_binS1(int* __restrict__ M, int* __restrict__ tot,
                                               int nb, int nblk)
{
    __shared__ int ps[256];
    int j = blockIdx.x, t = threadIdx.x;
    int i0 = 2 * t, i1 = 2 * t + 1;
    int v0 = (i0 < nblk) ? M[i0 * nb + j] : 0;
    int v1 = (i1 < nblk) ? M[i1 * nb + j] : 0;
    ps[t] = v0 + v1;
    __syncthreads();
    for (int off = 1; off < 256; off <<= 1) {
        int x = (t >= off) ? ps[t - off] : 0;
        __syncthreads();
        ps[t] += x;
        __syncthreads();
    }
    int ep = ps[t] - (v0 + v1);
    if (i0 < nblk) M[i0 * nb + j] = ep;
    if (i1 < nblk) M[i1 * nb + j] = ep + v0;
    if (t == 255) tot[j] = ps[255];
}

__global__ __launch_bounds__(256) void k_binS2(const int* __restrict__ tot, int* __restrict__ base, int nb)
{
    __shared__ int s[256];
    int t = threadIdx.x;
    int v = (t < nb) ? tot[t] : 0;
    s[t] = v;
    __syncthreads();
    for (int off = 1; off < 256; off <<= 1) {
        int x = (t >= off) ? s[t - off] : 0;
        __syncthreads();
        s[t] += x;
        __syncthreads();
    }
    if (t < nb) base[t] = s[t] - v;
    if (t == 255) base[nb] = s[255];
}

__global__ __launch_bounds__(256) void k_binB(const int* __restrict__ rows, const int* __restrict__ cols,
                                              const float* __restrict__ vals,
                                              const int* __restrict__ Mu, const int* __restrict__ Mi,
                                              const int* __restrict__ base_u, const int* __restrict__ base_i,
                                              int2* __restrict__ bu, int2* __restrict__ bi,
                                              int nnz, int chunk, int nbu, int nbi, int shu, int shi)
{
    __shared__ int cu[256], ci[256];
    int k = blockIdx.x, t = threadIdx.x;
    for (int j = t; j < nbu; j += 256) cu[j] = Mu[k * nbu + j] + base_u[j];
    for (int j = t; j < nbi; j += 256) ci[j] = Mi[k * nbi + j] + base_i[j];
    __syncthreads();
    int mu = (1 << shu) - 1, mi = (1 << shi) - 1;
    int beg = k * chunk, end = min(beg + chunk, nnz);
    if (beg >= end) return;
    int beg4 = beg >> 2, end4 = end >> 2;
    for (int e4 = beg4 + t; e4 < end4; e4 += 256) {
        int4 r = reinterpret_cast<const int4*>(rows)[e4];
        int4 c = reinterpret_cast<const int4*>(cols)[e4];
        int4 v = reinterpret_cast<const int4*>(vals)[e4];
        int p;
        p = atomicAdd(&cu[r.x >> shu], 1); bu[p] = make_int2((c.x << shu) | (r.x & mu), v.x);
        p = atomicAdd(&ci[c.x >> shi], 1); bi[p] = make_int2((r.x << shi) | (c.x & mi), v.x);
        p = atomicAdd(&cu[r.y >> shu], 1); bu[p] = make_int2((c.y << shu) | (r.y & mu), v.y);
        p = atomicAdd(&ci[c.y >> shi], 1); bi[p] = make_int2((r.y << shi) | (c.y & mi), v.y);
        p = atomicAdd(&cu[r.z >> shu], 1); bu[p] = make_int2((c.z << shu) | (r.z & mu), v.z);
        p = atomicAdd(&ci[c.z >> shi], 1); bi[p] = make_int2((r.z << shi) | (c.z & mi), v.z);
        p = atomicAdd(&cu[r.w >> shu], 1); bu[p] = make_int2((c.w << shu) | (r.w & mu), v.w);
        p = atomicAdd(&ci[c.w >> shi], 1); bi[p] = make_int2((r.w << shi) | (c.w & mi), v.w);
    }
    for (int e = (end4 << 2) + t; e < end; e += 256) {
        int r = rows[e], c = cols[e];
        int v = reinterpret_cast<const int*>(vals)[e];
        int p;
        p = atomicAdd(&cu[r >> shu], 1); bu[p] = make_int2((c << shu) | (r & mu), v);
        p = atomicAdd(&ci[c >> shi], 1); bi[p] = make_int2((r << shi) | (c & mi), v);
    }
}

__global__ __launch_bounds__(256) void k_binC(const int2* __restrict__ binned,
                                              const int* __restrict__ base,
                                              int* __restrict__ ptr, int2* __restrict__ cs,
                                              int nrows, int sh, int total)
{
    __shared__ int hist[512];
    __shared__ int scn[512];
    __shared__ int psum[256];
    int j = blockIdx.x, t = threadIdx.x;
    int BR = 1 << sh;
    int row0 = j << sh;
    int beg = base[j], end = base[j + 1];
    for (int r = t; r < BR; r += 256) hist[r] = 0;
    __syncthreads();
    for (int e = beg + t; e < end; e += 256)
        atomicAdd(&hist[binned[e].x & (BR - 1)], 1);
    __syncthreads();
    int v0 = (2 * t < BR) ? hist[2 * t] : 0;
    int v1 = (2 * t + 1 < BR) ? hist[2 * t + 1] : 0;
    psum[t] = v0 + v1;
    __syncthreads();
    for (int off = 1; off < 256; off <<= 1) {
        int x = (t >= off) ? psum[t - off] : 0;
        __syncthreads();
        psum[t] += x;
        __syncthreads();
    }
    int ep = psum[t] - (v0 + v1);
    if (2 * t < BR) scn[2 * t] = ep;
    if (2 * t + 1 < BR) scn[2 * t + 1] = ep + v0;
    __syncthreads();
    for (int r = t; r < BR; r += 256) {
        int row = row0 + r;
        if (row < nrows) ptr[row] = beg + scn[r];
        hist[r] = 0;
    }
    if (j == 0 && t == 0) ptr[nrows] = total;
    __syncthreads();
    for (int e = beg + t; e < end; e += 256) {
        int2 rec = binned[e];
        int rl = rec.x & (BR - 1);
        int pos = beg + scn[rl] + atomicAdd(&hist[rl], 1);
        cs[pos] = make_int2(((unsigned)rec.x) >> sh, rec.y);
    }
}

// ======================= f32 -> bf16 array convert =======================
__global__ void k_tobf(const float* __restrict__ in, unsigned short* __restrict__ out, int n8)
{
    int i = blockIdx.x * 256 + threadIdx.x;
    if (i >= n8) return;
    float4 a = reinterpret_cast<const float4*>(in)[2 * i];
    float4 c = reinterpret_cast<const float4*>(in)[2 * i + 1];
    uint4 o;
    o.x = (unsigned)f2bf(a.x) | ((unsigned)f2bf(a.y) << 16);
    o.y = (unsigned)f2bf(a.z) | ((unsigned)f2bf(a.w) << 16);
    o.z = (unsigned)f2bf(c.x) | ((unsigned)f2bf(c.y) << 16);
    o.w = (unsigned)f2bf(c.z) | ((unsigned)f2bf(c.w) << 16);
    reinterpret_cast<uint4*>(out)[i] = o;
}

// ===== batched gather core: 8 edges per step, coalesced pairs + shfl broadcast =====
__device__ __forceinline__ void gather8(const int2* __restrict__ pairs,
                                        const unsigned short* __restrict__ src,
                                        int beg, int end, int lr, int gb,
                                        float* __restrict__ acc)
{
    for (int base = beg; base < end; base += 8) {
        int2 pl = make_int2(0, 0);
        if (lr < 8 && base + lr < end) pl = pairs[base + lr];
        int   idx[8];
        float vv[8];
        #pragma unroll
        for (int e = 0; e < 8; ++e) {
            idx[e] = __shfl(pl.x, gb + e, 64);
            vv[e]  = __int_as_float(__shfl(pl.y, gb + e, 64));
        }
        v8s s[8];
        #pragma unroll
        for (int e = 0; e < 8; ++e)
            s[e] = *reinterpret_cast<const v8s*>(src + (long long)idx[e] * DIM + 8 * lr);
        #pragma unroll
        for (int e = 0; e < 8; ++e) {
            #pragma unroll
            for (int k = 0; k < 8; ++k)
                acc[k] += vv[e] * bf2f(s[e][k]);
        }
    }
}

// ======================= gather SpMM, bf16 source (16 lanes/row) ==========
__global__ __launch_bounds__(256) void k_spmm_bf(const int* __restrict__ ptr, const int2* __restrict__ pairs,
                                                 const unsigned short* __restrict__ src,
                                                 float* __restrict__ dst, int nrows)
{
    int r = blockIdx.x * 16 + (threadIdx.x >> 4);
    if (r >= nrows) return;
    int lr = threadIdx.x & 15;
    int gb = (threadIdx.x & 63) & ~15;
    int beg = ptr[r], end = ptr[r + 1];
    float acc[8];
    #pragma unroll
    for (int k = 0; k < 8; ++k) acc[k] = 0.f;
    gather8(pairs, src, beg, end, lr, gb, acc);
    float4 o0, o1;
    o0.x = acc[0]; o0.y = acc[1]; o0.z = acc[2]; o0.w = acc[3];
    o1.x = acc[4]; o1.y = acc[5]; o1.z = acc[6]; o1.w = acc[7];
    float* dp = dst + (long long)r * DIM + 8 * lr;
    *reinterpret_cast<float4*>(dp) = o0;
    *reinterpret_cast<float4*>(dp + 4) = o1;
}

// ======================= gather SpMM f32 (fallback paths) =======================
__global__ __launch_bounds__(256) void k_spmm4(const int* __restrict__ ptr, const int2* __restrict__ pairs,
                                               const float* __restrict__ src, float* __restrict__ dst, int nrows)
{
    int r = blockIdx.x * 8 + (threadIdx.x >> 5);
    if (r >= nrows) return;
    int l = threadIdx.x & 31;
    int beg = ptr[r], end = ptr[r + 1];
    float4 a0 = {0.f, 0.f, 0.f, 0.f}, a1 = {0.f, 0.f, 0.f, 0.f};
    int j = beg;
    for (; j + 1 < end; j += 2) {
        int2 p0 = pairs[j], p1 = pairs[j + 1];
        float v0 = __int_as_float(p0.y), v1 = __int_as_float(p1.y);
        float4 s0 = *reinterpret_cast<const float4*>(src + (long long)p0.x * DIM + 4 * l);
        float4 s1 = *reinterpret_cast<const float4*>(src + (long long)p1.x * DIM + 4 * l);
        a0.x += v0 * s0.x; a0.y += v0 * s0.y; a0.z += v0 * s0.z; a0.w += v0 * s0.w;
        a1.x += v1 * s1.x; a1.y += v1 * s1.y; a1.z += v1 * s1.z; a1.w += v1 * s1.w;
    }
    if (j < end) {
        int2 p0 = pairs[j];
        float v0 = __int_as_float(p0.y);
        float4 s0 = *reinterpret_cast<const float4*>(src + (long long)p0.x * DIM + 4 * l);
        a0.x += v0 * s0.x; a0.y += v0 * s0.y; a0.z += v0 * s0.z; a0.w += v0 * s0.w;
    }
    a0.x += a1.x; a0.y += a1.y; a0.z += a1.z; a0.w += a1.w;
    *reinterpret_cast<float4*>(dst + (long long)r * DIM + 4 * l) = a0;
}

// ======================= Bsw pack: W[c][k] f32 -> bf16 MFMA-B layout =======================
__global__ void k_bsw(const float* __restrict__ W, unsigned short* __restrict__ Bsw)
{
    int i = blockIdx.x * 256 + threadIdx.x;      // 0..32767
    int kt = i >> 12;
    int rem = i & 4095;
    int c = rem >> 5;
    int kk = rem & 31;
    Bsw[i] = f2bf(W[c * 256 + kt * 32 + kk]);
}

// ======================= FUSED: u-side gather SpMM + gate + bf16 MFMA linear ==========
// 256 thr = 4 waves; each wave owns 16 users + a private 8.4 KB cat slice.
__global__ __launch_bounds__(256) void k_fused(const int* __restrict__ ptr,
                                               const int2* __restrict__ pairs,
                                               const unsigned short* __restrict__ itbf,
                                               const float* __restrict__ ue,
                                               const unsigned short* __restrict__ Bsw,
                                               const float* __restrict__ b,
                                               float* __restrict__ msg,
                                               unsigned short* __restrict__ msg_bf, int nu)
{
    __shared__ unsigned short cat[4][16 * 264];  // 33792 B
    int tid = threadIdx.x;
    int w = tid >> 6, l = tid & 63;
    int lr = l & 15, hi = l >> 4;
    int gb = l & ~15;
    int d = lr * 8;
    int uw = blockIdx.x * 64 + w * 16;
    unsigned short* mycat = &cat[w][0];

    #pragma unroll
    for (int p = 0; p < 4; ++p) {
        int ur = p * 4 + hi;                     // 0..15
        int u = uw + ur;
        float acc[8];
        #pragma unroll
        for (int k = 0; k < 8; ++k) acc[k] = 0.f;
        float4 ue0 = make_float4(0.f,0.f,0.f,0.f), ue1 = make_float4(0.f,0.f,0.f,0.f);
        if (u < nu) {
            ue0 = *reinterpret_cast<const float4*>(ue + (long long)u * DIM + d);
            ue1 = *reinterpret_cast<const float4*>(ue + (long long)u * DIM + d + 4);
            int beg = ptr[u], end = ptr[u + 1];
            gather8(pairs, itbf, beg, end, lr, gb, acc);
        }
        float uev[8] = {ue0.x, ue0.y, ue0.z, ue0.w, ue1.x, ue1.y, ue1.z, ue1.w};
        uint4 nmp, gp;
        nmp.x = (unsigned)f2bf(acc[0]) | ((unsigned)f2bf(acc[1]) << 16);
        nmp.y = (unsigned)f2bf(acc[2]) | ((unsigned)f2bf(acc[3]) << 16);
        nmp.z = (unsigned)f2bf(acc[4]) | ((unsigned)f2bf(acc[5]) << 16);
        nmp.w = (unsigned)f2bf(acc[6]) | ((unsigned)f2bf(acc[7]) << 16);
        gp.x = (unsigned)f2bf(acc[0] * uev[0]) | ((unsigned)f2bf(acc[1] * uev[1]) << 16);
        gp.y = (unsigned)f2bf(acc[2] * uev[2]) | ((unsigned)f2bf(acc[3] * uev[3]) << 16);
        gp.z = (unsigned)f2bf(acc[4] * uev[4]) | ((unsigned)f2bf(acc[5] * uev[5]) << 16);
        gp.w = (unsigned)f2bf(acc[6] * uev[6]) | ((unsigned)f2bf(acc[7] * uev[7]) << 16);
        *reinterpret_cast<uint4*>(mycat + ur * 264 + d) = nmp;
        *reinterpret_cast<uint4*>(mycat + ur * 264 + 128 + d) = gp;
    }
    __syncthreads();

    v4f facc[8];
    #pragma unroll
    for (int ct = 0; ct < 8; ++ct) facc[ct] = (v4f){0.f, 0.f, 0.f, 0.f};
    const unsigned short* arow = mycat + lr * 264;
    for (int kt = 0; kt < 8; ++kt) {
        v8s a = *reinterpret_cast<const v8s*>(arow + kt * 32 + hi * 8);
        #pragma unroll
        for (int ct = 0; ct < 8; ++ct) {
            v8s bb = *reinterpret_cast<const v8s*>(Bsw + kt * 4096 + (ct * 16 + lr) * 32 + hi * 8);
            facc[ct] = __builtin_amdgcn_mfma_f32_16x16x32_bf16(a, bb, facc[ct], 0, 0, 0);
        }
    }

    int ub = uw + hi * 4;
    #pragma unroll
    for (int ct = 0; ct < 8; ++ct) {
        float bc = b[ct * 16 + lr];
        #pragma unroll
        for (int j = 0; j < 4; ++j) {
            int u = ub + j;
            if (u < nu) {
                float val = facc[ct][j] + bc;
                long long p = (long long)u * DIM + ct * 16 + lr;
                msg[p] = val;
                msg_bf[p] = f2bf(val);
            }
        }
    }
}

// ======================= unfused linear (R9 fallback) =======================
__global__ __launch_bounds__(256) void k_msg5(const float* __restrict__ nm_in,
                                              const float* __restrict__ ue,
                                              const unsigned short* __restrict__ Bsw,
                                              const float* __restrict__ b,
                                              float* __restrict__ msg,
                                              unsigned short* __restrict__ msg_bf, int nu)
{
    __shared__ unsigned short cat[64 * 264];
    int tid = threadIdx.x;
    int u0 = blockIdx.x * 64;

    for (int idx = tid; idx < 2048; idx += 256) {
        int u = idx >> 5, d4 = idx & 31;
        float4 nm4 = make_float4(0.f, 0.f, 0.f, 0.f);
        float4 ue4 = make_float4(0.f, 0.f, 0.f, 0.f);
        if (u0 + u < nu) {
            long long p = (long long)(u0 + u) * DIM + d4 * 4;
            nm4 = *reinterpret_cast<const float4*>(nm_in + p);
            ue4 = *reinterpret_cast<const float4*>(ue + p);
        }
        unsigned short* row = cat + u * 264;
        uint2 nmp, gp;
        nmp.x = (unsigned)f2bf(nm4.x) | ((unsigned)f2bf(nm4.y) << 16);
        nmp.y = (unsigned)f2bf(nm4.z) | ((unsigned)f2bf(nm4.w) << 16);
        gp.x  = (unsigned)f2bf(nm4.x * ue4.x) | ((unsigned)f2bf(nm4.y * ue4.y) << 16);
        gp.y  = (unsigned)f2bf(nm4.z * ue4.z) | ((unsigned)f2bf(nm4.w * ue4.w) << 16);
        *reinterpret_cast<uint2*>(row + d4 * 4) = nmp;
        *reinterpret_cast<uint2*>(row + 128 + d4 * 4) = gp;
    }
    __syncthreads();

    int l = tid & 63, w = tid >> 6;
    int lr = l & 15, hi = l >> 4;
    v4f acc[8];
    #pragma unroll
    for (int ct = 0; ct < 8; ++ct) acc[ct] = (v4f){0.f, 0.f, 0.f, 0.f};

    const unsigned short* arow = cat + (w * 16 + lr) * 264;
    for (int kt = 0; kt < 8; ++kt) {
        v8s a = *reinterpret_cast<const v8s*>(arow + kt * 32 + hi * 8);
        #pragma unroll
        for (int ct = 0; ct < 8; ++ct) {
            v8s bb = *reinterpret_cast<const v8s*>(Bsw + kt * 4096 + (ct * 16 + lr) * 32 + hi * 8);
            acc[ct] = __builtin_amdgcn_mfma_f32_16x16x32_bf16(a, bb, acc[ct], 0, 0, 0);
        }
    }

    int ub = u0 + w * 16 + hi * 4;
    #pragma unroll
    for (int ct = 0; ct < 8; ++ct) {
        float bc = b[ct * 16 + lr];
        #pragma unroll
        for (int j = 0; j < 4; ++j) {
            int u = ub + j;
            if (u < nu) {
                float val = acc[ct][j] + bc;
                long long p = (long long)u * DIM + ct * 16 + lr;
                msg[p] = val;
                msg_bf[p] = f2bf(val);
            }
        }
    }
}

// ======================= f32 linear (R5 fallback path) =======================
__global__ void k_wt(const float* __restrict__ W, float* __restrict__ Wt)
{
    int t = blockIdx.x * 256 + threadIdx.x;
    int k = t >> 7;
    int c = t & 127;
    Wt[t] = W[c * 256 + k];
}

#define UPB 32
#define CATP 260

__global__ __launch_bounds__(256) void k_msg4(const float* __restrict__ nm_in,
                                              const float* __restrict__ ue,
                                              const float* __restrict__ Wt,
                                              const float* __restrict__ b,
                                              float* __restrict__ msg, int nu)
{
    __shared__ float cat[UPB * CATP];
    int tid = threadIdx.x;
    int u0 = blockIdx.x * UPB;
    for (int idx = tid; idx < UPB * DIM; idx += 256) {
        int u = idx >> 7, d = idx & 127;
        float nm = 0.f, g = 0.f;
        if (u0 + u < nu) {
            long long p = (long long)(u0 + u) * DIM + d;
            nm = nm_in[p];
            g = nm * ue[p];
        }
        cat[u * CATP + d] = nm;
        cat[u * CATP + DIM + d] = g;
    }
    __syncthreads();

    int tc = tid & 31;
    int tu = tid >> 5;
    float acc[4][4];
    #pragma unroll
    for (int r = 0; r < 4; ++r)
        #pragma unroll
        for (int c = 0; c < 4; ++c) acc[r][c] = 0.f;

    const float* cbase = &cat[(tu * 4) * CATP];
    for (int k4 = 0; k4 < 64; ++k4) {
        float4 w[4];
        #pragma unroll
        for (int kk = 0; kk < 4; ++kk)
            w[kk] = *reinterpret_cast<const float4*>(Wt + (k4 * 4 + kk) * DIM + tc * 4);
        #pragma unroll
        for (int r = 0; r < 4; ++r) {
            float4 a = *reinterpret_cast<const float4*>(cbase + r * CATP + k4 * 4);
            acc[r][0] += a.x * w[0].x + a.y * w[1].x + a.z * w[2].x + a.w * w[3].x;
            acc[r][1] += a.x * w[0].y + a.y * w[1].y + a.z * w[2].y + a.w * w[3].y;
            acc[r][2] += a.x * w[0].z + a.y * w[1].z + a.z * w[2].z + a.w * w[3].z;
            acc[r][3] += a.x * w[0].w + a.y * w[1].w + a.z * w[2].w + a.w * w[3].w;
        }
    }

    float4 bb = *reinterpret_cast<const float4*>(b + tc * 4);
    #pragma unroll
    for (int r = 0; r < 4; ++r) {
        int u = u0 + tu * 4 + r;
        if (u < nu) {
            float4 o;
            o.x = acc[r][0] + bb.x; o.y = acc[r][1] + bb.y;
            o.z = acc[r][2] + bb.z; o.w = acc[r][3] + bb.w;
            *reinterpret_cast<float4*>(msg + (long long)u * DIM + tc * 4) = o;
        }
    }
}

// ======================= fallback: direct-scatter CSR build =======================

__global__ void k_count(const int* __restrict__ rows, const int* __restrict__ cols,
                        int* __restrict__ cnt_u, int* __restrict__ cnt_i, int nnz4, int nnz)
{
    int i = blockIdx.x * blockDim.x + threadIdx.x;
    int stride = gridDim.x * blockDim.x;
    for (int e4 = i; e4 < nnz4; e4 += stride) {
        int4 r = reinterpret_cast<const int4*>(rows)[e4];
        int4 c = reinterpret_cast<const int4*>(cols)[e4];
        atomicAdd(&cnt_u[r.x], 1); atomicAdd(&cnt_u[r.y], 1);
        atomicAdd(&cnt_u[r.z], 1); atomicAdd(&cnt_u[r.w], 1);
        atomicAdd(&cnt_i[c.x], 1); atomicAdd(&cnt_i[c.y], 1);
        atomicAdd(&cnt_i[c.z], 1); atomicAdd(&cnt_i[c.w], 1);
    }
    for (int e = nnz4 * 4 + i; e < nnz; e += stride) {
        atomicAdd(&cnt_u[rows[e]], 1);
        atomicAdd(&cnt_i[cols[e]], 1);
    }
}

__global__ void k_scan1(const int* __restrict__ cnt, int* __restrict__ ptr,
                        int* __restrict__ partial, int n)
{
    __shared__ int s[256];
    int i = blockIdx.x * 256 + threadIdx.x;
    int v = (i < n) ? cnt[i] : 0;
    s[threadIdx.x] = v;
    __syncthreads();
    for (int off = 1; off < 256; off <<= 1) {
        int x = (threadIdx.x >= off) ? s[threadIdx.x - off] : 0;
        __syncthreads();
        s[threadIdx.x] += x;
        __syncthreads();
    }
    if (i < n) ptr[i] = s[threadIdx.x] - v;
    if (threadIdx.x == 255) partial[blockIdx.x] = s[255];
}

__global__ void k_scan2(int* __restrict__ partial, int n)
{
    __shared__ int s[512];
    int v = (threadIdx.x < (unsigned)n) ? partial[threadIdx.x] : 0;
    s[threadIdx.x] = v;
    __syncthreads();
    for (int off = 1; off < 512; off <<= 1) {
        int x = (threadIdx.x >= off) ? s[threadIdx.x - off] : 0;
        __syncthreads();
        s[threadIdx.x] += x;
        __syncthreads();
    }
    if (threadIdx.x < (unsigned)n) partial[threadIdx.x] = s[threadIdx.x] - v;
}

__global__ void k_scan3(int* __restrict__ ptr, const int* __restrict__ partial,
                        int* __restrict__ woff, int n, int total)
{
    int i = blockIdx.x * 256 + threadIdx.x;
    if (i < n) {
        int p = ptr[i] + partial[blockIdx.x];
        ptr[i] = p;
        woff[i] = p;
        if (i == n - 1) ptr[n] = total;
    }
}

__global__ void k_edge_scatter(const int* __restrict__ rows, const int* __restrict__ cols,
                               const float* __restrict__ vals,
                               int* __restrict__ woff_u, int* __restrict__ woff_i,
                               int2* __restrict__ cs_u, int2* __restrict__ cs_i,
                               int nnz4, int nnz)
{
    int i = blockIdx.x * blockDim.x + threadIdx.x;
    int stride = gridDim.x * blockDim.x;
    for (int e4 = i; e4 < nnz4; e4 += stride) {
        int4 r = reinterpret_cast<const int4*>(rows)[e4];
        int4 c = reinterpret_cast<const int4*>(cols)[e4];
        float4 v = reinterpret_cast<const float4*>(vals)[e4];
        int pu, pi;
        pu = atomicAdd(&woff_u[r.x], 1); cs_u[pu] = make_int2(c.x, __float_as_int(v.x));
        pi = atomicAdd(&woff_i[c.x], 1); cs_i[pi] = make_int2(r.x, __float_as_int(v.x));
        pu = atomicAdd(&woff_u[r.y], 1); cs_u[pu] = make_int2(c.y, __float_as_int(v.y));
        pi = atomicAdd(&woff_i[c.y], 1); cs_i[pi] = make_int2(r.y, __float_as_int(v.y));
        pu = atomicAdd(&woff_u[r.z], 1); cs_u[pu] = make_int2(c.z, __float_as_int(v.z));
        pi = atomicAdd(&woff_i[c.z], 1); cs_i[pi] = make_int2(r.z, __float_as_int(v.z));
        pu = atomicAdd(&woff_u[r.w], 1); cs_u[pu] = make_int2(c.w, __float_as_int(v.w));
        pi = atomicAdd(&woff_i[c.w], 1); cs_i[pi] = make_int2(r.w, __float_as_int(v.w));
    }
    for (int e = nnz4 * 4 + i; e < nnz; e += stride) {
        int r = rows[e], c = cols[e];
        float v = vals[e];
        int pu = atomicAdd(&woff_u[r], 1); cs_u[pu] = make_int2(c, __float_as_int(v));
        int pi = atomicAdd(&woff_i[c], 1); cs_i[pi] = make_int2(r, __float_as_int(v));
    }
}

// ======================= fallback: atomic path =======================

__global__ void k_scatter(const int* __restrict__ didx, const int* __restrict__ sidx,
                          const float* __restrict__ vals, const float* __restrict__ src,
                          float* __restrict__ dst, long long nnz)
{
    long long t = (long long)blockIdx.x * blockDim.x + threadIdx.x;
    long long total = nnz * 32;
    if (t >= total) return;
    long long e = t >> 5;
    int d = (int)(t & 31) * 4;
    int si = sidx[e];
    int di = didx[e];
    float v = vals[e];
    const float4 s = *reinterpret_cast<const float4*>(src + (long long)si * DIM + d);
    float* p = dst + (long long)di * DIM + d;
    atomicAdd(p + 0, v * s.x);
    atomicAdd(p + 1, v * s.y);
    atomicAdd(p + 2, v * s.z);
    atomicAdd(p + 3, v * s.w);
}

__global__ void k_msg_simple(const float* __restrict__ user_emb, const float* __restrict__ W,
                             const float* __restrict__ b, float* __restrict__ msg)
{
    __shared__ float cat[2 * DIM];
    int u = blockIdx.x;
    int t = threadIdx.x;
    long long base = (long long)u * DIM;
    float nm = msg[base + t];
    float ue = user_emb[base + t];
    cat[t] = nm;
    cat[DIM + t] = nm * ue;
    __syncthreads();
    float acc = b[t];
    const float4* Wr = reinterpret_cast<const float4*>(W + (long long)t * 2 * DIM);
    const float4* c4 = reinterpret_cast<const float4*>(cat);
    #pragma unroll
    for (int k = 0; k < 2 * DIM / 4; ++k) {
        float4 w = Wr[k];
        float4 c = c4[k];
        acc += w.x * c.x + w.y * c.y + w.z * c.z + w.w * c.w;
    }
    msg[base + t] = acc;
}

// ======================= launch =======================

extern "C" void kernel_launch(void* const* d_in, const int* in_sizes, int n_in,
                              void* d_out, int out_size, void* d_ws, size_t ws_size,
                              hipStream_t stream) {
    const float* user_emb = (const float*)d_in[0];
    const float* item_emb = (const float*)d_in[1];
    const int*   rows     = (const int*)d_in[2];
    const int*   cols     = (const int*)d_in[3];
    const float* vals     = (const float*)d_in[4];
    const float* W        = (const float*)d_in[5];
    const float* b        = (const float*)d_in[6];

    int nu = in_sizes[0] / DIM;
    int ni = in_sizes[1] / DIM;
    int nnz = in_sizes[2];

    float* norm_emb = (float*)d_out;                              // [ni, DIM]
    float* msg      = (float*)d_out + (long long)ni * DIM;        // [nu, DIM]

    auto align256 = [](size_t x) { return (x + 255) & ~(size_t)255; };

    int shu = 0; while ((((long long)nu + (1LL << shu) - 1) >> shu) > 256) shu++;
    int shi = 0; while ((((long long)ni + (1LL << shi) - 1) >> shi) > 256) shi++;
    int nbu = (int)(((long long)nu + (1LL << shu) - 1) >> shu);
    int nbi = (int)(((long long)ni + (1LL << shi) - 1) >> shi);
    int chunk = (((nnz + NB - 1) / NB) + 3) & ~3;

    // ---- shared base layout (binned paths) ----
    size_t off = 0;
    size_t o_bu    = off; off = align256(off + (size_t)nnz * 8);
    size_t o_bi    = off; off = align256(off + (size_t)nnz * 8);
    size_t o_csu   = off; off = align256(off + (size_t)nnz * 8);
    size_t o_Mu    = off; off = align256(off + (size_t)NB * nbu * 4);
    size_t o_Mi    = off; off = align256(off + (size_t)NB * nbi * 4);
    size_t o_totu  = off; off = align256(off + (size_t)nbu * 4);
    size_t o_toti  = off; off = align256(off + (size_t)nbi * 4);
    size_t o_baseu = off; off = align256(off + (size_t)(nbu + 1) * 4);
    size_t o_basei = off; off = align256(off + (size_t)(nbi + 1) * 4);
    size_t o_ptru  = off; off = align256(off + (size_t)(nu + 1) * 4);
    size_t o_ptri  = off; off = align256(off + (size_t)(ni + 1) * 4);
    size_t o_bsw   = off; off = align256(off + (size_t)32768 * 2);
    size_t need_base = off;

    size_t itbf_need  = (size_t)ni * DIM * 2;
    size_t msgbf_need = (size_t)nu * DIM * 2;
    bool alias_it = (o_csu - o_bi) >= itbf_need;   // itbf in bi (dead after binC_i)

    // fused layout: msgbf appended (cs_u stays live during fused kernel)
    size_t need_fused = need_base;
    size_t o_msgbf_f = need_fused; need_fused = align256(need_fused + msgbf_need);
    size_t o_itbf_f;
    if (alias_it) o_itbf_f = o_bi;
    else { o_itbf_f = need_fused; need_fused = align256(need_fused + itbf_need); }

    // R9 (unfused) layout: msgbf may alias bi+csu (dead after spmm_u)
    size_t need_r9 = need_base;
    bool alias_msg = (o_Mu - o_bi) >= msgbf_need;
    size_t o_itbf_9, o_msgbf_9;
    if (alias_it) o_itbf_9 = o_bi;
    else { o_itbf_9 = need_r9; need_r9 = align256(need_r9 + itbf_need); }
    if (alias_msg) o_msgbf_9 = o_bi;
    else { o_msgbf_9 = need_r9; need_r9 = align256(need_r9 + msgbf_need); }

    bool pack_ok = ((long long)ni < (1LL << (31 - shu))) && ((long long)nu < (1LL << (31 - shi)))
                   && (shu <= 9) && (shi <= 9);

    // ---- R5-path layout ----
    off = 0;
    size_t o_cs_u   = off; off = align256(off + (size_t)nnz * 8);
    size_t o_cs_i   = off; off = align256(off + (size_t)nnz * 8);
    size_t o_ptr_u  = off; off = align256(off + (size_t)(nu + 1) * 4);
    size_t o_ptr_i  = off; off = align256(off + (size_t)(ni + 1) * 4);
    size_t o_woff_u = off; off = align256(off + (size_t)nu * 4);
    size_t o_woff_i = off; off = align256(off + (size_t)ni * 4);
    size_t o_part_u = off; off = align256(off + 512 * 4);
    size_t o_part_i = off; off = align256(off + 512 * 4);
    size_t o_wt2    = off; off = align256(off + (size_t)256 * DIM * 4);
    size_t need_r5 = off;

    int npb_u = (nu + 255) / 256;
    int npb_i = (ni + 255) / 256;

    char* ws = (char*)d_ws;

    if (pack_ok && (ws_size >= need_fused || ws_size >= need_r9)) {
        bool fused = (ws_size >= need_fused);
        int2* bu     = (int2*)(ws + o_bu);
        int2* bi     = (int2*)(ws + o_bi);
        int2* cs_u   = (int2*)(ws + o_csu);
        int2* cs_i   = (int2*)(ws + o_bu);     // alias: binned_u dead after binC_u
        int*  Mu     = (int*)(ws + o_Mu);
        int*  Mi     = (int*)(ws + o_Mi);
        int*  totu   = (int*)(ws + o_totu);
        int*  toti   = (int*)(ws + o_toti);
        int*  baseu  = (int*)(ws + o_baseu);
        int*  basei  = (int*)(ws + o_basei);
        int*  ptr_u  = (int*)(ws + o_ptru);
        int*  ptr_i  = (int*)(ws + o_ptri);
        unsigned short* bsw   = (unsigned short*)(ws + o_bsw);
        unsigned short* itbf  = (unsigned short*)(ws + (fused ? o_itbf_f : o_itbf_9));
        unsigned short* msgbf = (unsigned short*)(ws + (fused ? o_msgbf_f : o_msgbf_9));

        k_binA<<<NB, 256, 0, stream>>>(rows, cols, Mu, Mi, nnz, chunk, nbu, nbi, shu, shi);
        k_bsw<<<128, 256, 0, stream>>>(W, bsw);
        k_binS1<<<nbu, 256, 0, stream>>>(Mu, totu, nbu, NB);
        k_binS1<<<nbi, 256, 0, stream>>>(Mi, toti, nbi, NB);
        k_binS2<<<1, 256, 0, stream>>>(totu, baseu, nbu);
        k_binS2<<<1, 256, 0, stream>>>(toti, basei, nbi);
        k_binB<<<NB, 256, 0, stream>>>(rows, cols, vals, Mu, Mi, baseu, basei,
                                       bu, bi, nnz, chunk, nbu, nbi, shu, shi);
        k_binC<<<nbu, 256, 0, stream>>>(bu, baseu, ptr_u, cs_u, nu, shu, nnz);
        k_binC<<<nbi, 256, 0, stream>>>(bi, basei, ptr_i, cs_i, ni, shi, nnz);

        int n8i = ni * DIM / 8;
        k_tobf<<<(n8i + 255) / 256, 256, 0, stream>>>(item_emb, itbf, n8i);

        if (fused) {
            // gather + gate + linear in one kernel; writes msg (f32) + msgbf (bf16)
            k_fused<<<(nu + 63) / 64, 256, 0, stream>>>(ptr_u, cs_u, itbf, user_emb,
                                                        bsw, b, msg, msgbf, nu);
        } else {
            k_spmm_bf<<<(nu + 15) / 16, 256, 0, stream>>>(ptr_u, cs_u, itbf, msg, nu);
            k_msg5<<<(nu + 63) / 64, 256, 0, stream>>>(msg, user_emb, bsw, b, msg, msgbf, nu);
        }
        // norm_emb = H^T @ msg(bf16)
        k_spmm_bf<<<(ni + 15) / 16, 256, 0, stream>>>(ptr_i, cs_i, msgbf, norm_emb, ni);
    } else if (ws_size >= need_r5 && npb_u <= 512 && npb_i <= 512) {
        int2*  cs_u   = (int2*)(ws + o_cs_u);
        int2*  cs_i   = (int2*)(ws + o_cs_i);
        int*   ptr_u  = (int*)(ws + o_ptr_u);
        int*   ptr_i  = (int*)(ws + o_ptr_i);
        int*   woff_u = (int*)(ws + o_woff_u);
        int*   woff_i = (int*)(ws + o_woff_i);
        int*   part_u = (int*)(ws + o_part_u);
        int*   part_i = (int*)(ws + o_part_i);
        float* wt     = (float*)(ws + o_wt2);

        hipMemsetAsync(woff_u, 0, (size_t)nu * 4, stream);
        hipMemsetAsync(woff_i, 0, (size_t)ni * 4, stream);

        int nnz4 = nnz / 4;
        int gs = 1024;
        k_count<<<gs, 256, 0, stream>>>(rows, cols, woff_u, woff_i, nnz4, nnz);
        k_wt<<<(256 * DIM) / 256, 256, 0, stream>>>(W, wt);

        k_scan1<<<npb_u, 256, 0, stream>>>(woff_u, ptr_u, part_u, nu);
        k_scan1<<<npb_i, 256, 0, stream>>>(woff_i, ptr_i, part_i, ni);
        k_scan2<<<1, 512, 0, stream>>>(part_u, npb_u);
        k_scan2<<<1, 512, 0, stream>>>(part_i, npb_i);
        k_scan3<<<npb_u, 256, 0, stream>>>(ptr_u, part_u, woff_u, nu, nnz);
        k_scan3<<<npb_i, 256, 0, stream>>>(ptr_i, part_i, woff_i, ni, nnz);

        k_edge_scatter<<<gs, 256, 0, stream>>>(rows, cols, vals, woff_u, woff_i,
                                               cs_u, cs_i, nnz4, nnz);

        k_spmm4<<<(nu + 7) / 8, 256, 0, stream>>>(ptr_u, cs_u, item_emb, msg, nu);
        k_msg4<<<(nu + UPB - 1) / UPB, 256, 0, stream>>>(msg, user_emb, wt, b, msg, nu);
        k_spmm4<<<(ni + 7) / 8, 256, 0, stream>>>(ptr_i, cs_i, msg, norm_emb, ni);
    } else {
        hipMemsetAsync(d_out, 0, (size_t)out_size * sizeof(float), stream);
        long long tot = (long long)nnz * 32;
        int blk = 256;
        long long nblk = (tot + blk - 1) / blk;
        k_scatter<<<(int)nblk, blk, 0, stream>>>(rows, cols, vals, item_emb, msg, nnz);
        k_msg_simple<<<nu, DIM, 0, stream>>>(user_emb, W, b, msg);
        k_scatter<<<(int)nblk, blk, 0, stream>>>(cols, rows, vals, msg, norm_emb, nnz);
    }
}

// Round 15
// 255.581 us; speedup vs baseline: 1.1176x; 1.0508x over previous
//
#include <hip/hip_runtime.h>

#define DIM 128
#define NB 512            // binning grid blocks (pass A/B)

typedef short v8s __attribute__((ext_vector_type(8)));
typedef float v4f __attribute__((ext_vector_type(4)));

__device__ __forceinline__ unsigned short f2bf(float f) {
    unsigned int x = __float_as_uint(f);
    unsigned int r = ((x >> 16) & 1u) + 0x7fffu;
    return (unsigned short)((x + r) >> 16);
}
__device__ __forceinline__ float bf2f(short s) {
    return __uint_as_float(((unsigned)(unsigned short)s) << 16);
}

// ======================= binned CSR build (no global atomics) =======================

__global__ __launch_bounds__(256) void k_binA(const int* __restrict__ rows, const int* __restrict__ cols,
                                              int* __restrict__ Mu, int* __restrict__ Mi,
                                              int nnz, int chunk, int nbu, int nbi, int shu, int shi)
{
    __shared__ int hu[256], hi[256];
    int k = blockIdx.x, t = threadIdx.x;
    for (int j = t; j < nbu; j += 256) hu[j] = 0;
    for (int j = t; j < nbi; j += 256) hi[j] = 0;
    __syncthreads();
    int beg = k * chunk, end = min(beg + chunk, nnz);
    if (beg < end) {
        int beg4 = beg >> 2, end4 = end >> 2;
        for (int e4 = beg4 + t; e4 < end4; e4 += 256) {
            int4 r = reinterpret_cast<const int4*>(rows)[e4];
            int4 c = reinterpret_cast<const int4*>(cols)[e4];
            atomicAdd(&hu[r.x >> shu], 1); atomicAdd(&hu[r.y >> shu], 1);
            atomicAdd(&hu[r.z >> shu], 1); atomicAdd(&hu[r.w >> shu], 1);
            atomicAdd(&hi[c.x >> shi], 1); atomicAdd(&hi[c.y >> shi], 1);
            atomicAdd(&hi[c.z >> shi], 1); atomicAdd(&hi[c.w >> shi], 1);
        }
        for (int e = (end4 << 2) + t; e < end; e += 256) {
            atomicAdd(&hu[rows[e] >> shu], 1);
            atomicAdd(&hi[cols[e] >> shi], 1);
        }
    }
    __syncthreads();
    for (int j = t; j < nbu; j += 256) Mu[k * nbu + j] = hu[j];
    for (int j = t; j < nbi; j += 256) Mi[k * nbi + j] = hi[j];
}

// merged per-bucket scan over blocks (u and i sides in one grid)
__global__ __launch_bounds__(256) void k_binS1m(int* __restrict__ Mu, int* __restrict__ totu, int nbu,
                                                int* __restrict__ Mi, int* __restrict__ toti, int nbi,
                                                int nblk)
{
    __shared__ int ps[256];
    int j = blockIdx.x, t = threadIdx.x;
    int* M; int* tot; int nb; int col;
    if (j < nbu) { M = Mu; tot = totu; nb = nbu; col = j; }
    else         { M = Mi; tot = toti; nb = nbi; col = j - nbu; }
    int i0 = 2 * t, i1 = 2 * t + 1;
    int v0 = (i0 < nblk) ? M[i0 * nb + col] : 0;
    int v1 = (i1 < nblk) ? M[i1 * nb + col] : 0;
    ps[t] = v0 + v1;
    __syncthreads();
    for (int off = 1; off < 256; off <<= 1) {
        int x = (t >= off) ? ps[t - off] : 0;
        __syncthreads();
        ps[t] += x;
        __syncthreads();
    }
    int ep = ps[t] - (v0 + v1);
    if (i0 < nblk) M[i0 * nb + col] = ep;
    if (i1 < nblk) M[i1 * nb + col] = ep + v0;
    if (t == 255) tot[col] = ps[255];
}

// merged bucket-total scan (block 0 = u side, block 1 = i side)
__global__ __launch_bounds__(256) void k_binS2m(const int* __restrict__ totu, int* __restrict__ baseu, int nbu,
                                                const int* __restrict__ toti, int* __restrict__ basei, int nbi)
{
    __shared__ int s[256];
    int t = threadIdx.x;
    const int* tot; int* base; int nb;
    if (blockIdx.x == 0) { tot = totu; base = baseu; nb = nbu; }
    else                 { tot = toti; base = basei; nb = nbi; }
    int v = (t < nb) ? tot[t] : 0;
    s[t] = v;
    __syncthreads();
    for (int off = 1; off < 256; off <<= 1) {
        int x = (t >= off) ? s[t - off] : 0;
        __syncthreads();
        s[t] += x;
        __syncthreads();
    }
    if (t < nb) base[t] = s[t] - v;
    if (t == 255) base[nb] = s[255];
}

__global__ __launch_bounds__(256) void k_binB(const int* __restrict__ rows, const int* __restrict__ cols,
                                              const float* __restrict__ vals,
                                              const int* __restrict__ Mu, const int* __restrict__ Mi,
                                              const int* __restrict__ base_u, const int* __restrict__ base_i,
                                              int2* __restrict__ bu, int2* __restrict__ bi,
                                              int nnz, int chunk, int nbu, int nbi, int shu, int shi)
{
    __shared__ int cu[256], ci[256];
    int k = blockIdx.x, t = threadIdx.x;
    for (int j = t; j < nbu; j += 256) cu[j] = Mu[k * nbu + j] + base_u[j];
    for (int j = t; j < nbi; j += 256) ci[j] = Mi[k * nbi + j] + base_i[j];
    __syncthreads();
    int mu = (1 << shu) - 1, mi = (1 << shi) - 1;
    int beg = k * chunk, end = min(beg + chunk, nnz);
    if (beg >= end) return;
    int beg4 = beg >> 2, end4 = end >> 2;
    for (int e4 = beg4 + t; e4 < end4; e4 += 256) {
        int4 r = reinterpret_cast<const int4*>(rows)[e4];
        int4 c = reinterpret_cast<const int4*>(cols)[e4];
        int4 v = reinterpret_cast<const int4*>(vals)[e4];
        int p;
        p = atomicAdd(&cu[r.x >> shu], 1); bu[p] = make_int2((c.x << shu) | (r.x & mu), v.x);
        p = atomicAdd(&ci[c.x >> shi], 1); bi[p] = make_int2((r.x << shi) | (c.x & mi), v.x);
        p = atomicAdd(&cu[r.y >> shu], 1); bu[p] = make_int2((c.y << shu) | (r.y & mu), v.y);
        p = atomicAdd(&ci[c.y >> shi], 1); bi[p] = make_int2((r.y << shi) | (c.y & mi), v.y);
        p = atomicAdd(&cu[r.z >> shu], 1); bu[p] = make_int2((c.z << shu) | (r.z & mu), v.z);
        p = atomicAdd(&ci[c.z >> shi], 1); bi[p] = make_int2((r.z << shi) | (c.z & mi), v.z);
        p = atomicAdd(&cu[r.w >> shu], 1); bu[p] = make_int2((c.w << shu) | (r.w & mu), v.w);
        p = atomicAdd(&ci[c.w >> shi], 1); bi[p] = make_int2((r.w << shi) | (c.w & mi), v.w);
    }
    for (int e = (end4 << 2) + t; e < end; e += 256) {
        int r = rows[e], c = cols[e];
        int v = reinterpret_cast<const int*>(vals)[e];
        int p;
        p = atomicAdd(&cu[r >> shu], 1); bu[p] = make_int2((c << shu) | (r & mu), v);
        p = atomicAdd(&ci[c >> shi], 1); bi[p] = make_int2((r << shi) | (c & mi), v);
    }
}

// merged pass C: u-side buckets [0,nbu), i-side buckets [nbu, nbu+nbi)
__global__ __launch_bounds__(256) void k_binCm(const int2* __restrict__ bu, const int* __restrict__ baseu,
                                               int* __restrict__ ptru, int2* __restrict__ csu, int nu_, int shu,
                                               const int2* __restrict__ bi, const int* __restrict__ basei,
                                               int* __restrict__ ptri, int2* __restrict__ csi, int ni_, int shi,
                                               int nbu, int total)
{
    __shared__ int hist[512];
    __shared__ int scn[512];
    __shared__ int psum[256];
    int j = blockIdx.x, t = threadIdx.x;
    const int2* binned; const int* base; int* ptr; int2* cs; int nrows, sh, lj;
    if (j < nbu) { binned = bu; base = baseu; ptr = ptru; cs = csu; nrows = nu_; sh = shu; lj = j; }
    else         { binned = bi; base = basei; ptr = ptri; cs = csi; nrows = ni_; sh = shi; lj = j - nbu; }
    int BR = 1 << sh;
    int row0 = lj << sh;
    int beg = base[lj], end = base[lj + 1];
    for (int r = t; r < BR; r += 256) hist[r] = 0;
    __syncthreads();
    for (int e = beg + t; e < end; e += 256)
        atomicAdd(&hist[binned[e].x & (BR - 1)], 1);
    __syncthreads();
    int v0 = (2 * t < BR) ? hist[2 * t] : 0;
    int v1 = (2 * t + 1 < BR) ? hist[2 * t + 1] : 0;
    psum[t] = v0 + v1;
    __syncthreads();
    for (int off = 1; off < 256; off <<= 1) {
        int x = (t >= off) ? psum[t - off] : 0;
        __syncthreads();
        psum[t] += x;
        __syncthreads();
    }
    int ep = psum[t] - (v0 + v1);
    if (2 * t < BR) scn[2 * t] = ep;
    if (2 * t + 1 < BR) scn[2 * t + 1] = ep + v0;
    __syncthreads();
    for (int r = t; r < BR; r += 256) {
        int row = row0 + r;
        if (row < nrows) ptr[row] = beg + scn[r];
        hist[r] = 0;
    }
    if (lj == 0 && t == 0) ptr[nrows] = total;
    __syncthreads();
    for (int e = beg + t; e < end; e += 256) {
        int2 rec = binned[e];
        int rl = rec.x & (BR - 1);
        int pos = beg + scn[rl] + atomicAdd(&hist[rl], 1);
        cs[pos] = make_int2(((unsigned)rec.x) >> sh, rec.y);
    }
}

// ======================= f32 -> bf16 array convert =======================
__global__ void k_tobf(const float* __restrict__ in, unsigned short* __restrict__ out, int n8)
{
    int i = blockIdx.x * 256 + threadIdx.x;
    if (i >= n8) return;
    float4 a = reinterpret_cast<const float4*>(in)[2 * i];
    float4 c = reinterpret_cast<const float4*>(in)[2 * i + 1];
    uint4 o;
    o.x = (unsigned)f2bf(a.x) | ((unsigned)f2bf(a.y) << 16);
    o.y = (unsigned)f2bf(a.z) | ((unsigned)f2bf(a.w) << 16);
    o.z = (unsigned)f2bf(c.x) | ((unsigned)f2bf(c.y) << 16);
    o.w = (unsigned)f2bf(c.z) | ((unsigned)f2bf(c.w) << 16);
    reinterpret_cast<uint4*>(out)[i] = o;
}

// ===== dual-row batched gather: lanes 0-7 feed row A, lanes 8-15 feed row B =====
// Two independent dependency chains per 16-lane group; padded lanes add 0 via row 0.
__device__ __forceinline__ void gather8x2(const int2* __restrict__ pairs,
                                          const unsigned short* __restrict__ src,
                                          int b0, int e0, int b1, int e1,
                                          int lr, int gb,
                                          float* __restrict__ acc0,
                                          float* __restrict__ acc1)
{
    while (b0 < e0 || b1 < e1) {
        int2 pl = make_int2(0, 0);
        if (lr < 8) {
            if (b0 + lr < e0) pl = pairs[b0 + lr];
        } else {
            int o = lr - 8;
            if (b1 + o < e1) pl = pairs[b1 + o];
        }
        int   idx[16];
        float vv[16];
        #pragma unroll
        for (int e = 0; e < 16; ++e) {
            idx[e] = __shfl(pl.x, gb + e, 64);
            vv[e]  = __int_as_float(__shfl(pl.y, gb + e, 64));
        }
        v8s sa[8], sb[8];
        #pragma unroll
        for (int e = 0; e < 8; ++e)
            sa[e] = *reinterpret_cast<const v8s*>(src + (long long)idx[e] * DIM + 8 * lr);
        #pragma unroll
        for (int e = 0; e < 8; ++e)
            sb[e] = *reinterpret_cast<const v8s*>(src + (long long)idx[8 + e] * DIM + 8 * lr);
        #pragma unroll
        for (int e = 0; e < 8; ++e) {
            #pragma unroll
            for (int k = 0; k < 8; ++k)
                acc0[k] += vv[e] * bf2f(sa[e][k]);
        }
        #pragma unroll
        for (int e = 0; e < 8; ++e) {
            #pragma unroll
            for (int k = 0; k < 8; ++k)
                acc1[k] += vv[8 + e] * bf2f(sb[e][k]);
        }
        b0 += 8; b1 += 8;
    }
}

// ======================= gather SpMM, bf16 source: 2 rows per 16-lane group ==========
__global__ __launch_bounds__(256) void k_spmm_bf(const int* __restrict__ ptr, const int2* __restrict__ pairs,
                                                 const unsigned short* __restrict__ src,
                                                 float* __restrict__ dst, int nrows)
{
    int g = threadIdx.x >> 4;                 // 0..15
    int r0 = blockIdx.x * 32 + g;
    int r1 = r0 + 16;
    int lr = threadIdx.x & 15;
    int gb = (threadIdx.x & 63) & ~15;
    int b0 = 0, e0 = 0, b1 = 0, e1 = 0;
    if (r0 < nrows) { b0 = ptr[r0]; e0 = ptr[r0 + 1]; }
    if (r1 < nrows) { b1 = ptr[r1]; e1 = ptr[r1 + 1]; }
    float acc0[8], acc1[8];
    #pragma unroll
    for (int k = 0; k < 8; ++k) { acc0[k] = 0.f; acc1[k] = 0.f; }
    gather8x2(pairs, src, b0, e0, b1, e1, lr, gb, acc0, acc1);
    if (r0 < nrows) {
        float* dp = dst + (long long)r0 * DIM + 8 * lr;
        float4 o0 = {acc0[0], acc0[1], acc0[2], acc0[3]};
        float4 o1 = {acc0[4], acc0[5], acc0[6], acc0[7]};
        *reinterpret_cast<float4*>(dp) = o0;
        *reinterpret_cast<float4*>(dp + 4) = o1;
    }
    if (r1 < nrows) {
        float* dp = dst + (long long)r1 * DIM + 8 * lr;
        float4 o0 = {acc1[0], acc1[1], acc1[2], acc1[3]};
        float4 o1 = {acc1[4], acc1[5], acc1[6], acc1[7]};
        *reinterpret_cast<float4*>(dp) = o0;
        *reinterpret_cast<float4*>(dp + 4) = o1;
    }
}

// ======================= gather SpMM f32 (R5 fallback) =======================
__global__ __launch_bounds__(256) void k_spmm4(const int* __restrict__ ptr, const int2* __restrict__ pairs,
                                               const float* __restrict__ src, float* __restrict__ dst, int nrows)
{
    int r = blockIdx.x * 8 + (threadIdx.x >> 5);
    if (r >= nrows) return;
    int l = threadIdx.x & 31;
    int beg = ptr[r], end = ptr[r + 1];
    float4 a0 = {0.f, 0.f, 0.f, 0.f}, a1 = {0.f, 0.f, 0.f, 0.f};
    int j = beg;
    for (; j + 1 < end; j += 2) {
        int2 p0 = pairs[j], p1 = pairs[j + 1];
        float v0 = __int_as_float(p0.y), v1 = __int_as_float(p1.y);
        float4 s0 = *reinterpret_cast<const float4*>(src + (long long)p0.x * DIM + 4 * l);
        float4 s1 = *reinterpret_cast<const float4*>(src + (long long)p1.x * DIM + 4 * l);
        a0.x += v0 * s0.x; a0.y += v0 * s0.y; a0.z += v0 * s0.z; a0.w += v0 * s0.w;
        a1.x += v1 * s1.x; a1.y += v1 * s1.y; a1.z += v1 * s1.z; a1.w += v1 * s1.w;
    }
    if (j < end) {
        int2 p0 = pairs[j];
        float v0 = __int_as_float(p0.y);
        float4 s0 = *reinterpret_cast<const float4*>(src + (long long)p0.x * DIM + 4 * l);
        a0.x += v0 * s0.x; a0.y += v0 * s0.y; a0.z += v0 * s0.z; a0.w += v0 * s0.w;
    }
    a0.x += a1.x; a0.y += a1.y; a0.z += a1.z; a0.w += a1.w;
    *reinterpret_cast<float4*>(dst + (long long)r * DIM + 4 * l) = a0;
}

// ======================= Bsw pack: W[c][k] f32 -> bf16 MFMA-B layout =======================
__global__ void k_bsw(const float* __restrict__ W, unsigned short* __restrict__ Bsw)
{
    int i = blockIdx.x * 256 + threadIdx.x;      // 0..32767
    int kt = i >> 12;
    int rem = i & 4095;
    int c = rem >> 5;
    int kk = rem & 31;
    Bsw[i] = f2bf(W[c * 256 + kt * 32 + kk]);
}

// ======================= FUSED: dual-chain gather + gate + bf16 MFMA linear ==========
// 256 thr = 4 waves; wave owns 16 users + private 8.4 KB cat slice.
// Phase 1: 2 pp-iterations, each gathers TWO users per 16-lane group (dual chains).
__global__ __launch_bounds__(256) void k_fused(const int* __restrict__ ptr,
                                               const int2* __restrict__ pairs,
                                               const unsigned short* __restrict__ itbf,
                                               const float* __restrict__ ue,
                                               const unsigned short* __restrict__ Bsw,
                                               const float* __restrict__ b,
                                               float* __restrict__ msg,
                                               unsigned short* __restrict__ msg_bf, int nu)
{
    __shared__ unsigned short cat[4][16 * 264];  // 33792 B
    int tid = threadIdx.x;
    int w = tid >> 6, l = tid & 63;
    int lr = l & 15, hi = l >> 4;
    int gb = l & ~15;
    int d = lr * 8;
    int uw = blockIdx.x * 64 + w * 16;
    unsigned short* mycat = &cat[w][0];

    #pragma unroll
    for (int pp = 0; pp < 2; ++pp) {
        int ur0 = pp * 4 + hi;                   // 0..7
        int ur1 = ur0 + 8;                       // 8..15
        int ua = uw + ur0, ub = uw + ur1;
        float acc0[8], acc1[8];
        #pragma unroll
        for (int k = 0; k < 8; ++k) { acc0[k] = 0.f; acc1[k] = 0.f; }
        float uev0[8], uev1[8];
        #pragma unroll
        for (int k = 0; k < 8; ++k) { uev0[k] = 0.f; uev1[k] = 0.f; }
        int b0 = 0, e0 = 0, b1 = 0, e1 = 0;
        if (ua < nu) {
            float4 x0 = *reinterpret_cast<const float4*>(ue + (long long)ua * DIM + d);
            float4 x1 = *reinterpret_cast<const float4*>(ue + (long long)ua * DIM + d + 4);
            uev0[0] = x0.x; uev0[1] = x0.y; uev0[2] = x0.z; uev0[3] = x0.w;
            uev0[4] = x1.x; uev0[5] = x1.y; uev0[6] = x1.z; uev0[7] = x1.w;
            b0 = ptr[ua]; e0 = ptr[ua + 1];
        }
        if (ub < nu) {
            float4 x0 = *reinterpret_cast<const float4*>(ue + (long long)ub * DIM + d);
            float4 x1 = *reinterpret_cast<const float4*>(ue + (long long)ub * DIM + d + 4);
            uev1[0] = x0.x; uev1[1] = x0.y; uev1[2] = x0.z; uev1[3] = x0.w;
            uev1[4] = x1.x; uev1[5] = x1.y; uev1[6] = x1.z; uev1[7] = x1.w;
            b1 = ptr[ub]; e1 = ptr[ub + 1];
        }
        gather8x2(pairs, itbf, b0, e0, b1, e1, lr, gb, acc0, acc1);

        uint4 nmp, gp;
        nmp.x = (unsigned)f2bf(acc0[0]) | ((unsigned)f2bf(acc0[1]) << 16);
        nmp.y = (unsigned)f2bf(acc0[2]) | ((unsigned)f2bf(acc0[3]) << 16);
        nmp.z = (unsigned)f2bf(acc0[4]) | ((unsigned)f2bf(acc0[5]) << 16);
        nmp.w = (unsigned)f2bf(acc0[6]) | ((unsigned)f2bf(acc0[7]) << 16);
        gp.x = (unsigned)f2bf(acc0[0] * uev0[0]) | ((unsigned)f2bf(acc0[1] * uev0[1]) << 16);
        gp.y = (unsigned)f2bf(acc0[2] * uev0[2]) | ((unsigned)f2bf(acc0[3] * uev0[3]) << 16);
        gp.z = (unsigned)f2bf(acc0[4] * uev0[4]) | ((unsigned)f2bf(acc0[5] * uev0[5]) << 16);
        gp.w = (unsigned)f2bf(acc0[6] * uev0[6]) | ((unsigned)f2bf(acc0[7] * uev0[7]) << 16);
        *reinterpret_cast<uint4*>(mycat + ur0 * 264 + d) = nmp;
        *reinterpret_cast<uint4*>(mycat + ur0 * 264 + 128 + d) = gp;

        nmp.x = (unsigned)f2bf(acc1[0]) | ((unsigned)f2bf(acc1[1]) << 16);
        nmp.y = (unsigned)f2bf(acc1[2]) | ((unsigned)f2bf(acc1[3]) << 16);
        nmp.z = (unsigned)f2bf(acc1[4]) | ((unsigned)f2bf(acc1[5]) << 16);
        nmp.w = (unsigned)f2bf(acc1[6]) | ((unsigned)f2bf(acc1[7]) << 16);
        gp.x = (unsigned)f2bf(acc1[0] * uev1[0]) | ((unsigned)f2bf(acc1[1] * uev1[1]) << 16);
        gp.y = (unsigned)f2bf(acc1[2] * uev1[2]) | ((unsigned)f2bf(acc1[3] * uev1[3]) << 16);
        gp.z = (unsigned)f2bf(acc1[4] * uev1[4]) | ((unsigned)f2bf(acc1[5] * uev1[5]) << 16);
        gp.w = (unsigned)f2bf(acc1[6] * uev1[6]) | ((unsigned)f2bf(acc1[7] * uev1[7]) << 16);
        *reinterpret_cast<uint4*>(mycat + ur1 * 264 + d) = nmp;
        *reinterpret_cast<uint4*>(mycat + ur1 * 264 + 128 + d) = gp;
    }
    __syncthreads();

    v4f facc[8];
    #pragma unroll
    for (int ct = 0; ct < 8; ++ct) facc[ct] = (v4f){0.f, 0.f, 0.f, 0.f};
    const unsigned short* arow = mycat + lr * 264;
    for (int kt = 0; kt < 8; ++kt) {
        v8s a = *reinterpret_cast<const v8s*>(arow + kt * 32 + hi * 8);
        #pragma unroll
        for (int ct = 0; ct < 8; ++ct) {
            v8s bb = *reinterpret_cast<const v8s*>(Bsw + kt * 4096 + (ct * 16 + lr) * 32 + hi * 8);
            facc[ct] = __builtin_amdgcn_mfma_f32_16x16x32_bf16(a, bb, facc[ct], 0, 0, 0);
        }
    }

    int ubase = uw + hi * 4;
    #pragma unroll
    for (int ct = 0; ct < 8; ++ct) {
        float bc = b[ct * 16 + lr];
        #pragma unroll
        for (int j = 0; j < 4; ++j) {
            int u = ubase + j;
            if (u < nu) {
                float val = facc[ct][j] + bc;
                long long p = (long long)u * DIM + ct * 16 + lr;
                msg[p] = val;
                msg_bf[p] = f2bf(val);
            }
        }
    }
}

// ======================= f32 linear (R5 fallback path) =======================
__global__ void k_wt(const float* __restrict__ W, float* __restrict__ Wt)
{
    int t = blockIdx.x * 256 + threadIdx.x;
    int k = t >> 7;
    int c = t & 127;
    Wt[t] = W[c * 256 + k];
}

#define UPB 32
#define CATP 260

__global__ __launch_bounds__(256) void k_msg4(const float* __restrict__ nm_in,
                                              const float* __restrict__ ue,
                                              const float* __restrict__ Wt,
                                              const float* __restrict__ b,
                                              float* __restrict__ msg, int nu)
{
    __shared__ float cat[UPB * CATP];
    int tid = threadIdx.x;
    int u0 = blockIdx.x * UPB;
    for (int idx = tid; idx < UPB * DIM; idx += 256) {
        int u = idx >> 7, d = idx & 127;
        float nm = 0.f, g = 0.f;
        if (u0 + u < nu) {
            long long p = (long long)(u0 + u) * DIM + d;
            nm = nm_in[p];
            g = nm * ue[p];
        }
        cat[u * CATP + d] = nm;
        cat[u * CATP + DIM + d] = g;
    }
    __syncthreads();

    int tc = tid & 31;
    int tu = tid >> 5;
    float acc[4][4];
    #pragma unroll
    for (int r = 0; r < 4; ++r)
        #pragma unroll
        for (int c = 0; c < 4; ++c) acc[r][c] = 0.f;

    const float* cbase = &cat[(tu * 4) * CATP];
    for (int k4 = 0; k4 < 64; ++k4) {
        float4 w[4];
        #pragma unroll
        for (int kk = 0; kk < 4; ++kk)
            w[kk] = *reinterpret_cast<const float4*>(Wt + (k4 * 4 + kk) * DIM + tc * 4);
        #pragma unroll
        for (int r = 0; r < 4; ++r) {
            float4 a = *reinterpret_cast<const float4*>(cbase + r * CATP + k4 * 4);
            acc[r][0] += a.x * w[0].x + a.y * w[1].x + a.z * w[2].x + a.w * w[3].x;
            acc[r][1] += a.x * w[0].y + a.y * w[1].y + a.z * w[2].y + a.w * w[3].y;
            acc[r][2] += a.x * w[0].z + a.y * w[1].z + a.z * w[2].z + a.w * w[3].z;
            acc[r][3] += a.x * w[0].w + a.y * w[1].w + a.z * w[2].w + a.w * w[3].w;
        }
    }

    float4 bb = *reinterpret_cast<const float4*>(b + tc * 4);
    #pragma unroll
    for (int r = 0; r < 4; ++r) {
        int u = u0 + tu * 4 + r;
        if (u < nu) {
            float4 o;
            o.x = acc[r][0] + bb.x; o.y = acc[r][1] + bb.y;
            o.z = acc[r][2] + bb.z; o.w = acc[r][3] + bb.w;
            *reinterpret_cast<float4*>(msg + (long long)u * DIM + tc * 4) = o;
        }
    }
}

// ======================= fallback: direct-scatter CSR build =======================

__global__ void k_count(const int* __restrict__ rows, const int* __restrict__ cols,
                        int* __restrict__ cnt_u, int* __restrict__ cnt_i, int nnz4, int nnz)
{
    int i = blockIdx.x * blockDim.x + threadIdx.x;
    int stride = gridDim.x * blockDim.x;
    for (int e4 = i; e4 < nnz4; e4 += stride) {
        int4 r = reinterpret_cast<const int4*>(rows)[e4];
        int4 c = reinterpret_cast<const int4*>(cols)[e4];
        atomicAdd(&cnt_u[r.x], 1); atomicAdd(&cnt_u[r.y], 1);
        atomicAdd(&cnt_u[r.z], 1); atomicAdd(&cnt_u[r.w], 1);
        atomicAdd(&cnt_i[c.x], 1); atomicAdd(&cnt_i[c.y], 1);
        atomicAdd(&cnt_i[c.z], 1); atomicAdd(&cnt_i[c.w], 1);
    }
    for (int e = nnz4 * 4 + i; e < nnz; e += stride) {
        atomicAdd(&cnt_u[rows[e]], 1);
        atomicAdd(&cnt_i[cols[e]], 1);
    }
}

__global__ void k_scan1(const int* __restrict__ cnt, int* __restrict__ ptr,
                        int* __restrict__ partial, int n)
{
    __shared__ int s[256];
    int i = blockIdx.x * 256 + threadIdx.x;
    int v = (i < n) ? cnt[i] : 0;
    s[threadIdx.x] = v;
    __syncthreads();
    for (int off = 1; off < 256; off <<= 1) {
        int x = (threadIdx.x >= off) ? s[threadIdx.x - off] : 0;
        __syncthreads();
        s[threadIdx.x] += x;
        __syncthreads();
    }
    if (i < n) ptr[i] = s[threadIdx.x] - v;
    if (threadIdx.x == 255) partial[blockIdx.x] = s[255];
}

__global__ void k_scan2(int* __restrict__ partial, int n)
{
    __shared__ int s[512];
    int v = (threadIdx.x < (unsigned)n) ? partial[threadIdx.x] : 0;
    s[threadIdx.x] = v;
    __syncthreads();
    for (int off = 1; off < 512; off <<= 1) {
        int x = (threadIdx.x >= off) ? s[threadIdx.x - off] : 0;
        __syncthreads();
        s[threadIdx.x] += x;
        __syncthreads();
    }
    if (threadIdx.x < (unsigned)n) partial[threadIdx.x] = s[threadIdx.x] - v;
}

__global__ void k_scan3(int* __restrict__ ptr, const int* __restrict__ partial,
                        int* __restrict__ woff, int n, int total)
{
    int i = blockIdx.x * 256 + threadIdx.x;
    if (i < n) {
        int p = ptr[i] + partial[blockIdx.x];
        ptr[i] = p;
        woff[i] = p;
        if (i == n - 1) ptr[n] = total;
    }
}

__global__ void k_edge_scatter(const int* __restrict__ rows, const int* __restrict__ cols,
                               const float* __restrict__ vals,
                               int* __restrict__ woff_u, int* __restrict__ woff_i,
                               int2* __restrict__ cs_u, int2* __restrict__ cs_i,
                               int nnz4, int nnz)
{
    int i = blockIdx.x * blockDim.x + threadIdx.x;
    int stride = gridDim.x * blockDim.x;
    for (int e4 = i; e4 < nnz4; e4 += stride) {
        int4 r = reinterpret_cast<const int4*>(rows)[e4];
        int4 c = reinterpret_cast<const int4*>(cols)[e4];
        float4 v = reinterpret_cast<const float4*>(vals)[e4];
        int pu, pi;
        pu = atomicAdd(&woff_u[r.x], 1); cs_u[pu] = make_int2(c.x, __float_as_int(v.x));
        pi = atomicAdd(&woff_i[c.x], 1); cs_i[pi] = make_int2(r.x, __float_as_int(v.x));
        pu = atomicAdd(&woff_u[r.y], 1); cs_u[pu] = make_int2(c.y, __float_as_int(v.y));
        pi = atomicAdd(&woff_i[c.y], 1); cs_i[pi] = make_int2(r.y, __float_as_int(v.y));
        pu = atomicAdd(&woff_u[r.z], 1); cs_u[pu] = make_int2(c.z, __float_as_int(v.z));
        pi = atomicAdd(&woff_i[c.z], 1); cs_i[pi] = make_int2(r.z, __float_as_int(v.z));
        pu = atomicAdd(&woff_u[r.w], 1); cs_u[pu] = make_int2(c.w, __float_as_int(v.w));
        pi = atomicAdd(&woff_i[c.w], 1); cs_i[pi] = make_int2(r.w, __float_as_int(v.w));
    }
    for (int e = nnz4 * 4 + i; e < nnz; e += stride) {
        int r = rows[e], c = cols[e];
        float v = vals[e];
        int pu = atomicAdd(&woff_u[r], 1); cs_u[pu] = make_int2(c, __float_as_int(v));
        int pi = atomicAdd(&woff_i[c], 1); cs_i[pi] = make_int2(r, __float_as_int(v));
    }
}

// ======================= fallback: atomic path =======================

__global__ void k_scatter(const int* __restrict__ didx, const int* __restrict__ sidx,
                          const float* __restrict__ vals, const float* __restrict__ src,
                          float* __restrict__ dst, long long nnz)
{
    long long t = (long long)blockIdx.x * blockDim.x + threadIdx.x;
    long long total = nnz * 32;
    if (t >= total) return;
    long long e = t >> 5;
    int d = (int)(t & 31) * 4;
    int si = sidx[e];
    int di = didx[e];
    float v = vals[e];
    const float4 s = *reinterpret_cast<const float4*>(src + (long long)si * DIM + d);
    float* p = dst + (long long)di * DIM + d;
    atomicAdd(p + 0, v * s.x);
    atomicAdd(p + 1, v * s.y);
    atomicAdd(p + 2, v * s.z);
    atomicAdd(p + 3, v * s.w);
}

__global__ void k_msg_simple(const float* __restrict__ user_emb, const float* __restrict__ W,
                             const float* __restrict__ b, float* __restrict__ msg)
{
    __shared__ float cat[2 * DIM];
    int u = blockIdx.x;
    int t = threadIdx.x;
    long long base = (long long)u * DIM;
    float nm = msg[base + t];
    float ue = user_emb[base + t];
    cat[t] = nm;
    cat[DIM + t] = nm * ue;
    __syncthreads();
    float acc = b[t];
    const float4* Wr = reinterpret_cast<const float4*>(W + (long long)t * 2 * DIM);
    const float4* c4 = reinterpret_cast<const float4*>(cat);
    #pragma unroll
    for (int k = 0; k < 2 * DIM / 4; ++k) {
        float4 w = Wr[k];
        float4 c = c4[k];
        acc += w.x * c.x + w.y * c.y + w.z * c.z + w.w * c.w;
    }
    msg[base + t] = acc;
}

// ======================= launch =======================

extern "C" void kernel_launch(void* const* d_in, const int* in_sizes, int n_in,
                              void* d_out, int out_size, void* d_ws, size_t ws_size,
                              hipStream_t stream) {
    const float* user_emb = (const float*)d_in[0];
    const float* item_emb = (const float*)d_in[1];
    const int*   rows     = (const int*)d_in[2];
    const int*   cols     = (const int*)d_in[3];
    const float* vals     = (const float*)d_in[4];
    const float* W        = (const float*)d_in[5];
    const float* b        = (const float*)d_in[6];

    int nu = in_sizes[0] / DIM;
    int ni = in_sizes[1] / DIM;
    int nnz = in_sizes[2];

    float* norm_emb = (float*)d_out;                              // [ni, DIM]
    float* msg      = (float*)d_out + (long long)ni * DIM;        // [nu, DIM]

    auto align256 = [](size_t x) { return (x + 255) & ~(size_t)255; };

    int shu = 0; while ((((long long)nu + (1LL << shu) - 1) >> shu) > 256) shu++;
    int shi = 0; while ((((long long)ni + (1LL << shi) - 1) >> shi) > 256) shi++;
    int nbu = (int)(((long long)nu + (1LL << shu) - 1) >> shu);
    int nbi = (int)(((long long)ni + (1LL << shi) - 1) >> shi);
    int chunk = (((nnz + NB - 1) / NB) + 3) & ~3;

    // ---- binned path layout (cs_i has its OWN region: merged binC needs no alias) ----
    size_t off = 0;
    size_t o_bu    = off; off = align256(off + (size_t)nnz * 8);
    size_t o_bi    = off; off = align256(off + (size_t)nnz * 8);
    size_t o_csu   = off; off = align256(off + (size_t)nnz * 8);
    size_t o_csi   = off; off = align256(off + (size_t)nnz * 8);
    size_t o_Mu    = off; off = align256(off + (size_t)NB * nbu * 4);
    size_t o_Mi    = off; off = align256(off + (size_t)NB * nbi * 4);
    size_t o_totu  = off; off = align256(off + (size_t)nbu * 4);
    size_t o_toti  = off; off = align256(off + (size_t)nbi * 4);
    size_t o_baseu = off; off = align256(off + (size_t)(nbu + 1) * 4);
    size_t o_basei = off; off = align256(off + (size_t)(nbi + 1) * 4);
    size_t o_ptru  = off; off = align256(off + (size_t)(nu + 1) * 4);
    size_t o_ptri  = off; off = align256(off + (size_t)(ni + 1) * 4);
    size_t o_bsw   = off; off = align256(off + (size_t)32768 * 2);
    size_t o_msgbf = off; off = align256(off + (size_t)nu * DIM * 2);
    size_t need_fused = off;

    size_t itbf_need = (size_t)ni * DIM * 2;
    bool alias_it = ((o_csu - o_bi) >= itbf_need);   // itbf overlays bu/bi? bi is dead after binCm; gap bi->csu
    size_t o_itbf;
    if (alias_it) o_itbf = o_bi;
    else { o_itbf = need_fused; need_fused = align256(need_fused + itbf_need); }

    bool pack_ok = ((long long)ni < (1LL << (31 - shu))) && ((long long)nu < (1LL << (31 - shi)))
                   && (shu <= 9) && (shi <= 9);

    // ---- R5-path layout ----
    off = 0;
    size_t o_cs_u   = off; off = align256(off + (size_t)nnz * 8);
    size_t o_cs_i   = off; off = align256(off + (size_t)nnz * 8);
    size_t o_ptr_u  = off; off = align256(off + (size_t)(nu + 1) * 4);
    size_t o_ptr_i  = off; off = align256(off + (size_t)(ni + 1) * 4);
    size_t o_woff_u = off; off = align256(off + (size_t)nu * 4);
    size_t o_woff_i = off; off = align256(off + (size_t)ni * 4);
    size_t o_part_u = off; off = align256(off + 512 * 4);
    size_t o_part_i = off; off = align256(off + 512 * 4);
    size_t o_wt2    = off; off = align256(off + (size_t)256 * DIM * 4);
    size_t need_r5 = off;

    int npb_u = (nu + 255) / 256;
    int npb_i = (ni + 255) / 256;

    char* ws = (char*)d_ws;

    if (pack_ok && ws_size >= need_fused) {
        int2* bu     = (int2*)(ws + o_bu);
        int2* bi     = (int2*)(ws + o_bi);
        int2* cs_u   = (int2*)(ws + o_csu);
        int2* cs_i   = (int2*)(ws + o_csi);
        int*  Mu     = (int*)(ws + o_Mu);
        int*  Mi     = (int*)(ws + o_Mi);
        int*  totu   = (int*)(ws + o_totu);
        int*  toti   = (int*)(ws + o_toti);
        int*  baseu  = (int*)(ws + o_baseu);
        int*  basei  = (int*)(ws + o_basei);
        int*  ptr_u  = (int*)(ws + o_ptru);
        int*  ptr_i  = (int*)(ws + o_ptri);
        unsigned short* bsw   = (unsigned short*)(ws + o_bsw);
        unsigned short* msgbf = (unsigned short*)(ws + o_msgbf);
        unsigned short* itbf  = (unsigned short*)(ws + o_itbf);

        k_binA<<<NB, 256, 0, stream>>>(rows, cols, Mu, Mi, nnz, chunk, nbu, nbi, shu, shi);
        k_bsw<<<128, 256, 0, stream>>>(W, bsw);
        k_binS1m<<<nbu + nbi, 256, 0, stream>>>(Mu, totu, nbu, Mi, toti, nbi, NB);
        k_binS2m<<<2, 256, 0, stream>>>(totu, baseu, nbu, toti, basei, nbi);
        k_binB<<<NB, 256, 0, stream>>>(rows, cols, vals, Mu, Mi, baseu, basei,
                                       bu, bi, nnz, chunk, nbu, nbi, shu, shi);
        k_binCm<<<nbu + nbi, 256, 0, stream>>>(bu, baseu, ptr_u, cs_u, nu, shu,
                                               bi, basei, ptr_i, cs_i, ni, shi,
                                               nbu, nnz);

        int n8i = ni * DIM / 8;
        k_tobf<<<(n8i + 255) / 256, 256, 0, stream>>>(item_emb, itbf, n8i);

        // gather + gate + linear in one kernel; writes msg (f32) + msgbf (bf16)
        k_fused<<<(nu + 63) / 64, 256, 0, stream>>>(ptr_u, cs_u, itbf, user_emb,
                                                    bsw, b, msg, msgbf, nu);
        // norm_emb = H^T @ msg(bf16)
        k_spmm_bf<<<(ni + 31) / 32, 256, 0, stream>>>(ptr_i, cs_i, msgbf, norm_emb, ni);
    } else if (ws_size >= need_r5 && npb_u <= 512 && npb_i <= 512) {
        int2*  cs_u   = (int2*)(ws + o_cs_u);
        int2*  cs_i   = (int2*)(ws + o_cs_i);
        int*   ptr_u  = (int*)(ws + o_ptr_u);
        int*   ptr_i  = (int*)(ws + o_ptr_i);
        int*   woff_u = (int*)(ws + o_woff_u);
        int*   woff_i = (int*)(ws + o_woff_i);
        int*   part_u = (int*)(ws + o_part_u);
        int*   part_i = (int*)(ws + o_part_i);
        float* wt     = (float*)(ws + o_wt2);

        hipMemsetAsync(woff_u, 0, (size_t)nu * 4, stream);
        hipMemsetAsync(woff_i, 0, (size_t)ni * 4, stream);

        int nnz4 = nnz / 4;
        int gs = 1024;
        k_count<<<gs, 256, 0, stream>>>(rows, cols, woff_u, woff_i, nnz4, nnz);
        k_wt<<<(256 * DIM) / 256, 256, 0, stream>>>(W, wt);

        k_scan1<<<npb_u, 256, 0, stream>>>(woff_u, ptr_u, part_u, nu);
        k_scan1<<<npb_i, 256, 0, stream>>>(woff_i, ptr_i, part_i, ni);
        k_scan2<<<1, 512, 0, stream>>>(part_u, npb_u);
        k_scan2<<<1, 512, 0, stream>>>(part_i, npb_i);
        k_scan3<<<npb_u, 256, 0, stream>>>(ptr_u, part_u, woff_u, nu, nnz);
        k_scan3<<<npb_i, 256, 0, stream>>>(ptr_i, part_i, woff_i, ni, nnz);

        k_edge_scatter<<<gs, 256, 0, stream>>>(rows, cols, vals, woff_u, woff_i,
                                               cs_u, cs_i, nnz4, nnz);

        k_spmm4<<<(nu + 7) / 8, 256, 0, stream>>>(ptr_u, cs_u, item_emb, msg, nu);
        k_msg4<<<(nu + UPB - 1) / UPB, 256, 0, stream>>>(msg, user_emb, wt, b, msg, nu);
        k_spmm4<<<(ni + 7) / 8, 256, 0, stream>>>(ptr_i, cs_i, msg, norm_emb, ni);
    } else {
        hipMemsetAsync(d_out, 0, (size_t)out_size * sizeof(float), stream);
        long long tot = (long long)nnz * 32;
        int blk = 256;
        long long nblk = (tot + blk - 1) / blk;
        k_scatter<<<(int)nblk, blk, 0, stream>>>(rows, cols, vals, item_emb, msg, nnz);
        k_msg_simple<<<nu, DIM, 0, stream>>>(user_emb, W, b, msg);
        k_scatter<<<(int)nblk, blk, 0, stream>>>(cols, rows, vals, msg, norm_emb, nnz);
    }
}